// Round 1
// baseline (3074.972 us; speedup 1.0000x reference)
//
#include <hip/hip_runtime.h>
#include <cstdint>
#include <cstddef>

#define N0C 262144
#define N1C 65536
#define N2C 16384
#define E1C 1048576
#define E2C 262144
// IN_C=128, HID_C=256, OUT_C=64

__global__ void zero_kernel(float4* __restrict__ p, int n4) {
  int i = blockIdx.x * blockDim.x + threadIdx.x;
  int stride = gridDim.x * blockDim.x;
  float4 z = make_float4(0.f, 0.f, 0.f, 0.f);
  for (; i < n4; i += stride) p[i] = z;
}

__global__ void count_kernel(const int* __restrict__ dst, int n, float* __restrict__ cnt) {
  int i = blockIdx.x * blockDim.x + threadIdx.x;
  if (i < n) unsafeAtomicAdd(&cnt[dst[i]], 1.0f);
}

// layer-1 scatter: 128 ch/edge, 32 lanes per edge, float4 per lane
__global__ void scatter1_kernel(const float* __restrict__ x, const int* __restrict__ src,
                                const int* __restrict__ dst, float* __restrict__ aggr) {
  int t = blockIdx.x * blockDim.x + threadIdx.x;
  int e = t >> 5;
  int half = t & 31;
  int s = src[e];
  int d = dst[e];
  float4 v = ((const float4*)(x + (size_t)s * 128))[half];
  float* ar = aggr + (size_t)d * 128 + half * 4;
  unsafeAtomicAdd(ar + 0, v.x);
  unsafeAtomicAdd(ar + 1, v.y);
  unsafeAtomicAdd(ar + 2, v.z);
  unsafeAtomicAdd(ar + 3, v.w);
}

// layer-2 scatter: 256 ch/edge, 64 lanes per edge, float4 per lane
__global__ void scatter2_kernel(const float* __restrict__ h1, const int* __restrict__ src,
                                const int* __restrict__ dst, float* __restrict__ aggr) {
  int t = blockIdx.x * blockDim.x + threadIdx.x;
  int e = t >> 6;
  int lane = t & 63;
  int s = src[e];
  int d = dst[e];
  float4 v = ((const float4*)(h1 + (size_t)s * 256))[lane];
  float* ar = aggr + (size_t)d * 256 + lane * 4;
  unsafeAtomicAdd(ar + 0, v.x);
  unsafeAtomicAdd(ar + 1, v.y);
  unsafeAtomicAdd(ar + 2, v.z);
  unsafeAtomicAdd(ar + 3, v.w);
}

// GEMM1: h1[i][o] = relu( (aggr1[i]/cnt1[i]) . W1l[o] + x[i] . W1r[o] + b1[o] )
// Tile 64 rows x 64 cols, K=256 (aggr|x concat). 256 threads, 4x4 per thread.
// LDS: sA[64][256], sW[64][256] as float4-chunks with XOR swizzle (chunk ^= (row>>2)&7).
__global__ __launch_bounds__(256) void gemm1_kernel(
    const float* __restrict__ aggr1, const float* __restrict__ cnt1,
    const float* __restrict__ x, const float* __restrict__ Wl,
    const float* __restrict__ Wr, const float* __restrict__ b,
    float* __restrict__ h1) {
  __shared__ float sA[64 * 256];
  __shared__ float sW[64 * 256];
  int t = threadIdx.x;
  int i0 = blockIdx.x * 64;
  int c0 = blockIdx.y * 64;

  // stage A: rows i0..i0+63; k 0..127 = aggr1/cnt, k 128..255 = x
  for (int p = 0; p < 16; ++p) {
    int idx = p * 256 + t;
    int row = idx >> 6;
    int c4 = idx & 63;
    int i = i0 + row;
    float4 v;
    if (c4 < 32) {
      v = ((const float4*)(aggr1 + (size_t)i * 128))[c4];
      float inv = 1.0f / fmaxf(cnt1[i], 1.0f);
      v.x *= inv; v.y *= inv; v.z *= inv; v.w *= inv;
    } else {
      v = ((const float4*)(x + (size_t)i * 128))[c4 - 32];
    }
    ((float4*)sA)[row * 64 + (c4 ^ ((row >> 2) & 7))] = v;
  }
  // stage W: rows c0..c0+63; k 0..127 = W1l, k 128..255 = W1r
  for (int p = 0; p < 16; ++p) {
    int idx = p * 256 + t;
    int c = idx >> 6;
    int k4 = idx & 63;
    float4 v;
    if (k4 < 32) v = ((const float4*)(Wl + (size_t)(c0 + c) * 128))[k4];
    else         v = ((const float4*)(Wr + (size_t)(c0 + c) * 128))[k4 - 32];
    ((float4*)sW)[c * 64 + (k4 ^ ((c >> 2) & 7))] = v;
  }
  __syncthreads();

  int tr = t >> 4;   // 0..15
  int tc = t & 15;   // 0..15
  float acc[4][4] = {{0.f}};
  for (int k4 = 0; k4 < 64; ++k4) {
    float4 av[4], wv[4];
#pragma unroll
    for (int jr = 0; jr < 4; ++jr) {
      int r = tr * 4 + jr;
      av[jr] = ((float4*)sA)[r * 64 + (k4 ^ ((r >> 2) & 7))];
    }
#pragma unroll
    for (int jc = 0; jc < 4; ++jc) {
      int c = tc * 4 + jc;
      wv[jc] = ((float4*)sW)[c * 64 + (k4 ^ ((c >> 2) & 7))];
    }
#pragma unroll
    for (int jr = 0; jr < 4; ++jr)
#pragma unroll
      for (int jc = 0; jc < 4; ++jc) {
        acc[jr][jc] += av[jr].x * wv[jc].x + av[jr].y * wv[jc].y +
                       av[jr].z * wv[jc].z + av[jr].w * wv[jc].w;
      }
  }

#pragma unroll
  for (int jr = 0; jr < 4; ++jr) {
    int i = i0 + tr * 4 + jr;
    int c = c0 + tc * 4;
    float4 o;
    o.x = fmaxf(acc[jr][0] + b[c + 0], 0.f);
    o.y = fmaxf(acc[jr][1] + b[c + 1], 0.f);
    o.z = fmaxf(acc[jr][2] + b[c + 2], 0.f);
    o.w = fmaxf(acc[jr][3] + b[c + 3], 0.f);
    *((float4*)(h1 + (size_t)i * 256 + c)) = o;
  }
}

// GEMM2 + bias + log_softmax: out[i][o] = logsm( (aggr2[i]/cnt2[i]).W2l[o] + h1[i].W2r[o] + b2[o] )
// Tile 64 rows x 64 cols (all cols), K=512 in two passes of 256.
__global__ __launch_bounds__(256) void gemm2_kernel(
    const float* __restrict__ aggr2, const float* __restrict__ cnt2,
    const float* __restrict__ h1, const float* __restrict__ W2l,
    const float* __restrict__ W2r, const float* __restrict__ b2,
    float* __restrict__ out) {
  __shared__ float sA[64 * 256];
  __shared__ float sW[64 * 256];
  int t = threadIdx.x;
  int i0 = blockIdx.x * 64;
  int tr = t >> 4;
  int tc = t & 15;
  float acc[4][4] = {{0.f}};

  for (int pass = 0; pass < 2; ++pass) {
    for (int p = 0; p < 16; ++p) {
      int idx = p * 256 + t;
      int row = idx >> 6;
      int c4 = idx & 63;
      int i = i0 + row;
      float4 v;
      if (pass == 0) {
        v = ((const float4*)(aggr2 + (size_t)i * 256))[c4];
        float inv = 1.0f / fmaxf(cnt2[i], 1.0f);
        v.x *= inv; v.y *= inv; v.z *= inv; v.w *= inv;
      } else {
        v = ((const float4*)(h1 + (size_t)i * 256))[c4];
      }
      ((float4*)sA)[row * 64 + (c4 ^ ((row >> 2) & 7))] = v;
    }
    const float* Wsrc = (pass == 0) ? W2l : W2r;
    for (int p = 0; p < 16; ++p) {
      int idx = p * 256 + t;
      int c = idx >> 6;
      int k4 = idx & 63;
      float4 v = ((const float4*)(Wsrc + (size_t)c * 256))[k4];
      ((float4*)sW)[c * 64 + (k4 ^ ((c >> 2) & 7))] = v;
    }
    __syncthreads();
    for (int k4 = 0; k4 < 64; ++k4) {
      float4 av[4], wv[4];
#pragma unroll
      for (int jr = 0; jr < 4; ++jr) {
        int r = tr * 4 + jr;
        av[jr] = ((float4*)sA)[r * 64 + (k4 ^ ((r >> 2) & 7))];
      }
#pragma unroll
      for (int jc = 0; jc < 4; ++jc) {
        int c = tc * 4 + jc;
        wv[jc] = ((float4*)sW)[c * 64 + (k4 ^ ((c >> 2) & 7))];
      }
#pragma unroll
      for (int jr = 0; jr < 4; ++jr)
#pragma unroll
        for (int jc = 0; jc < 4; ++jc) {
          acc[jr][jc] += av[jr].x * wv[jc].x + av[jr].y * wv[jc].y +
                         av[jr].z * wv[jc].z + av[jr].w * wv[jc].w;
        }
    }
    __syncthreads();
  }

  // epilogue: bias, then per-row log_softmax over the 64 cols
  float* sOut = sA;              // [64][68]
  float* sM = sA + 64 * 68;      // [64]
  float* sL = sM + 64;           // [64]
#pragma unroll
  for (int jr = 0; jr < 4; ++jr)
#pragma unroll
    for (int jc = 0; jc < 4; ++jc) {
      int r = tr * 4 + jr;
      int c = tc * 4 + jc;
      sOut[r * 68 + c] = acc[jr][jc] + b2[c];
    }
  __syncthreads();

  int w = t >> 6;
  int lane = t & 63;
  int row = w * 16 + (lane & 15);
  int cg = lane >> 4;
  float m = -1e30f;
  for (int j = 0; j < 16; ++j) m = fmaxf(m, sOut[row * 68 + cg * 16 + j]);
  m = fmaxf(m, __shfl_xor(m, 16));
  m = fmaxf(m, __shfl_xor(m, 32));
  float ssum = 0.f;
  for (int j = 0; j < 16; ++j) ssum += __expf(sOut[row * 68 + cg * 16 + j] - m);
  ssum += __shfl_xor(ssum, 16);
  ssum += __shfl_xor(ssum, 32);
  if (cg == 0) { sM[row] = m; sL[row] = __logf(ssum); }
  __syncthreads();

  int orow = t >> 2;
  int seg = t & 3;
  float mm = sM[orow];
  float ll = sL[orow];
#pragma unroll
  for (int j = 0; j < 4; ++j) {
    float4 v = *(float4*)&sOut[orow * 68 + seg * 16 + j * 4];
    float4 o = make_float4(v.x - mm - ll, v.y - mm - ll, v.z - mm - ll, v.w - mm - ll);
    ((float4*)(out + (size_t)(i0 + orow) * 64))[seg * 4 + j] = o;
  }
}

extern "C" void kernel_launch(void* const* d_in, const int* in_sizes, int n_in,
                              void* d_out, int out_size, void* d_ws, size_t ws_size,
                              hipStream_t stream) {
  const float* x   = (const float*)d_in[0];
  const int* src1  = (const int*)d_in[1];
  const int* dst1  = (const int*)d_in[2];
  const int* src2  = (const int*)d_in[3];
  const int* dst2  = (const int*)d_in[4];
  const float* W1l = (const float*)d_in[5];
  const float* W1r = (const float*)d_in[6];
  const float* b1  = (const float*)d_in[7];
  const float* W2l = (const float*)d_in[8];
  const float* W2r = (const float*)d_in[9];
  const float* b2  = (const float*)d_in[10];
  float* out = (float*)d_out;

  float* ws = (float*)d_ws;
  float* aggr1 = ws;                                  // N1*128
  float* aggr2 = aggr1 + (size_t)N1C * 128;           // N2*256
  float* cnt1  = aggr2 + (size_t)N2C * 256;           // N1
  float* cnt2  = cnt1 + N1C;                          // N2
  float* h1    = cnt2 + N2C;                          // N1*256

  int zero_n4 = (N1C * 128 + N2C * 256 + N1C + N2C) / 4;
  zero_kernel<<<4096, 256, 0, stream>>>((float4*)ws, zero_n4);
  count_kernel<<<E1C / 256, 256, 0, stream>>>(dst1, E1C, cnt1);
  count_kernel<<<E2C / 256, 256, 0, stream>>>(dst2, E2C, cnt2);
  scatter1_kernel<<<E1C / 8, 256, 0, stream>>>(x, src1, dst1, aggr1);
  gemm1_kernel<<<dim3(N1C / 64, 4), 256, 0, stream>>>(aggr1, cnt1, x, W1l, W1r, b1, h1);
  scatter2_kernel<<<E2C / 4, 256, 0, stream>>>(h1, src2, dst2, aggr2);
  gemm2_kernel<<<N2C / 64, 256, 0, stream>>>(aggr2, cnt2, h1, W2l, W2r, b2, out);
}

// Round 2
// 503.358 us; speedup vs baseline: 6.1089x; 6.1089x over previous
//
#include <hip/hip_runtime.h>
#include <cstdint>
#include <cstddef>

#define N0C 262144
#define N1C 65536
#define N2C 16384
#define E1C 1048576
#define E2C 262144
// IN_C=128, HID_C=256, OUT_C=64

// ---------------- CSR build: histogram -> scan -> edge scatter ----------------

__global__ void hist_kernel(const int* __restrict__ dst, int n, int* __restrict__ cnt) {
  int i = blockIdx.x * blockDim.x + threadIdx.x;
  if (i < n) atomicAdd(&cnt[dst[i]], 1);
}

// block-level inclusive scan (256 elems/block) -> exclusive result + block sums
__global__ __launch_bounds__(256) void scan1_kernel(const int* __restrict__ cnt,
                                                    int* __restrict__ excl,
                                                    int* __restrict__ bsum) {
  __shared__ int s[256];
  int t = threadIdx.x;
  int i = blockIdx.x * 256 + t;
  int v = cnt[i];
  s[t] = v;
  __syncthreads();
  for (int ofs = 1; ofs < 256; ofs <<= 1) {
    int add = (t >= ofs) ? s[t - ofs] : 0;
    __syncthreads();
    s[t] += add;
    __syncthreads();
  }
  excl[i] = s[t] - v;
  if (t == 255) bsum[blockIdx.x] = s[255];
}

// single-block exclusive scan of block sums (nb <= 256)
__global__ __launch_bounds__(256) void scan2_kernel(int* __restrict__ bsum, int nb) {
  __shared__ int s[256];
  int t = threadIdx.x;
  int v = (t < nb) ? bsum[t] : 0;
  s[t] = v;
  __syncthreads();
  for (int ofs = 1; ofs < 256; ofs <<= 1) {
    int add = (t >= ofs) ? s[t - ofs] : 0;
    __syncthreads();
    s[t] += add;
    __syncthreads();
  }
  if (t < nb) bsum[t] = s[t] - v;
}

// add block bases; emit final offsets + a mutable fill copy
__global__ __launch_bounds__(256) void scan3_kernel(int* __restrict__ excl,
                                                    const int* __restrict__ bsum,
                                                    int* __restrict__ fill) {
  int i = blockIdx.x * 256 + threadIdx.x;
  int v = excl[i] + bsum[blockIdx.x];
  excl[i] = v;
  fill[i] = v;
}

__global__ void sortedge_kernel(const int* __restrict__ src, const int* __restrict__ dst,
                                int n, int* __restrict__ fill, int* __restrict__ ssrc) {
  int i = blockIdx.x * blockDim.x + threadIdx.x;
  if (i < n) {
    int d = dst[i];
    int pos = atomicAdd(&fill[d], 1);
    ssrc[pos] = src[i];
  }
}

// ---------------- gather-based mean aggregation (one wave per dst) ----------------

// layer 1: 128 ch, float2 per lane
__global__ __launch_bounds__(256) void agg1_kernel(const float* __restrict__ x,
                                                   const int* __restrict__ ssrc,
                                                   const int* __restrict__ off,
                                                   const int* __restrict__ cnt,
                                                   float* __restrict__ aggr) {
  int wid = (blockIdx.x * 256 + threadIdx.x) >> 6;
  int lane = threadIdx.x & 63;
  int start = off[wid];
  int n = cnt[wid];
  float2 acc = make_float2(0.f, 0.f);
  int j = 0;
  for (; j + 4 <= n; j += 4) {
    int s0 = ssrc[start + j + 0];
    int s1 = ssrc[start + j + 1];
    int s2 = ssrc[start + j + 2];
    int s3 = ssrc[start + j + 3];
    float2 v0 = ((const float2*)(x + (size_t)s0 * 128))[lane];
    float2 v1 = ((const float2*)(x + (size_t)s1 * 128))[lane];
    float2 v2 = ((const float2*)(x + (size_t)s2 * 128))[lane];
    float2 v3 = ((const float2*)(x + (size_t)s3 * 128))[lane];
    acc.x += v0.x + v1.x + v2.x + v3.x;
    acc.y += v0.y + v1.y + v2.y + v3.y;
  }
  for (; j < n; ++j) {
    int s = ssrc[start + j];
    float2 v = ((const float2*)(x + (size_t)s * 128))[lane];
    acc.x += v.x;
    acc.y += v.y;
  }
  float inv = (n > 0) ? 1.0f / (float)n : 0.f;
  ((float2*)(aggr + (size_t)wid * 128))[lane] = make_float2(acc.x * inv, acc.y * inv);
}

// layer 2: 256 ch, float4 per lane
__global__ __launch_bounds__(256) void agg2_kernel(const float* __restrict__ h1,
                                                   const int* __restrict__ ssrc,
                                                   const int* __restrict__ off,
                                                   const int* __restrict__ cnt,
                                                   float* __restrict__ aggr) {
  int wid = (blockIdx.x * 256 + threadIdx.x) >> 6;
  int lane = threadIdx.x & 63;
  int start = off[wid];
  int n = cnt[wid];
  float4 acc = make_float4(0.f, 0.f, 0.f, 0.f);
  int j = 0;
  for (; j + 4 <= n; j += 4) {
    int s0 = ssrc[start + j + 0];
    int s1 = ssrc[start + j + 1];
    int s2 = ssrc[start + j + 2];
    int s3 = ssrc[start + j + 3];
    float4 v0 = ((const float4*)(h1 + (size_t)s0 * 256))[lane];
    float4 v1 = ((const float4*)(h1 + (size_t)s1 * 256))[lane];
    float4 v2 = ((const float4*)(h1 + (size_t)s2 * 256))[lane];
    float4 v3 = ((const float4*)(h1 + (size_t)s3 * 256))[lane];
    acc.x += v0.x + v1.x + v2.x + v3.x;
    acc.y += v0.y + v1.y + v2.y + v3.y;
    acc.z += v0.z + v1.z + v2.z + v3.z;
    acc.w += v0.w + v1.w + v2.w + v3.w;
  }
  for (; j < n; ++j) {
    int s = ssrc[start + j];
    float4 v = ((const float4*)(h1 + (size_t)s * 256))[lane];
    acc.x += v.x;
    acc.y += v.y;
    acc.z += v.z;
    acc.w += v.w;
  }
  float inv = (n > 0) ? 1.0f / (float)n : 0.f;
  ((float4*)(aggr + (size_t)wid * 256))[lane] =
      make_float4(acc.x * inv, acc.y * inv, acc.z * inv, acc.w * inv);
}

// ---------------- GEMMs (aggr pre-normalized) ----------------

// GEMM1: h1[i][o] = relu( aggr1[i] . W1l[o] + x[i] . W1r[o] + b1[o] )
__global__ __launch_bounds__(256) void gemm1_kernel(
    const float* __restrict__ aggr1, const float* __restrict__ x,
    const float* __restrict__ Wl, const float* __restrict__ Wr,
    const float* __restrict__ b, float* __restrict__ h1) {
  __shared__ float sA[64 * 256];
  __shared__ float sW[64 * 256];
  int t = threadIdx.x;
  int i0 = blockIdx.x * 64;
  int c0 = blockIdx.y * 64;

  for (int p = 0; p < 16; ++p) {
    int idx = p * 256 + t;
    int row = idx >> 6;
    int c4 = idx & 63;
    int i = i0 + row;
    float4 v;
    if (c4 < 32) v = ((const float4*)(aggr1 + (size_t)i * 128))[c4];
    else         v = ((const float4*)(x + (size_t)i * 128))[c4 - 32];
    ((float4*)sA)[row * 64 + (c4 ^ ((row >> 2) & 7))] = v;
  }
  for (int p = 0; p < 16; ++p) {
    int idx = p * 256 + t;
    int c = idx >> 6;
    int k4 = idx & 63;
    float4 v;
    if (k4 < 32) v = ((const float4*)(Wl + (size_t)(c0 + c) * 128))[k4];
    else         v = ((const float4*)(Wr + (size_t)(c0 + c) * 128))[k4 - 32];
    ((float4*)sW)[c * 64 + (k4 ^ ((c >> 2) & 7))] = v;
  }
  __syncthreads();

  int tr = t >> 4;
  int tc = t & 15;
  float acc[4][4] = {{0.f}};
  for (int k4 = 0; k4 < 64; ++k4) {
    float4 av[4], wv[4];
#pragma unroll
    for (int jr = 0; jr < 4; ++jr) {
      int r = tr * 4 + jr;
      av[jr] = ((float4*)sA)[r * 64 + (k4 ^ ((r >> 2) & 7))];
    }
#pragma unroll
    for (int jc = 0; jc < 4; ++jc) {
      int c = tc * 4 + jc;
      wv[jc] = ((float4*)sW)[c * 64 + (k4 ^ ((c >> 2) & 7))];
    }
#pragma unroll
    for (int jr = 0; jr < 4; ++jr)
#pragma unroll
      for (int jc = 0; jc < 4; ++jc) {
        acc[jr][jc] += av[jr].x * wv[jc].x + av[jr].y * wv[jc].y +
                       av[jr].z * wv[jc].z + av[jr].w * wv[jc].w;
      }
  }

#pragma unroll
  for (int jr = 0; jr < 4; ++jr) {
    int i = i0 + tr * 4 + jr;
    int c = c0 + tc * 4;
    float4 o;
    o.x = fmaxf(acc[jr][0] + b[c + 0], 0.f);
    o.y = fmaxf(acc[jr][1] + b[c + 1], 0.f);
    o.z = fmaxf(acc[jr][2] + b[c + 2], 0.f);
    o.w = fmaxf(acc[jr][3] + b[c + 3], 0.f);
    *((float4*)(h1 + (size_t)i * 256 + c)) = o;
  }
}

// GEMM2 + bias + log_softmax
__global__ __launch_bounds__(256) void gemm2_kernel(
    const float* __restrict__ aggr2, const float* __restrict__ h1,
    const float* __restrict__ W2l, const float* __restrict__ W2r,
    const float* __restrict__ b2, float* __restrict__ out) {
  __shared__ float sA[64 * 256];
  __shared__ float sW[64 * 256];
  int t = threadIdx.x;
  int i0 = blockIdx.x * 64;
  int tr = t >> 4;
  int tc = t & 15;
  float acc[4][4] = {{0.f}};

  for (int pass = 0; pass < 2; ++pass) {
    const float* Asrc = (pass == 0) ? aggr2 : h1;
    const float* Wsrc = (pass == 0) ? W2l : W2r;
    for (int p = 0; p < 16; ++p) {
      int idx = p * 256 + t;
      int row = idx >> 6;
      int c4 = idx & 63;
      float4 v = ((const float4*)(Asrc + (size_t)(i0 + row) * 256))[c4];
      ((float4*)sA)[row * 64 + (c4 ^ ((row >> 2) & 7))] = v;
    }
    for (int p = 0; p < 16; ++p) {
      int idx = p * 256 + t;
      int c = idx >> 6;
      int k4 = idx & 63;
      float4 v = ((const float4*)(Wsrc + (size_t)c * 256))[k4];
      ((float4*)sW)[c * 64 + (k4 ^ ((c >> 2) & 7))] = v;
    }
    __syncthreads();
    for (int k4 = 0; k4 < 64; ++k4) {
      float4 av[4], wv[4];
#pragma unroll
      for (int jr = 0; jr < 4; ++jr) {
        int r = tr * 4 + jr;
        av[jr] = ((float4*)sA)[r * 64 + (k4 ^ ((r >> 2) & 7))];
      }
#pragma unroll
      for (int jc = 0; jc < 4; ++jc) {
        int c = tc * 4 + jc;
        wv[jc] = ((float4*)sW)[c * 64 + (k4 ^ ((c >> 2) & 7))];
      }
#pragma unroll
      for (int jr = 0; jr < 4; ++jr)
#pragma unroll
        for (int jc = 0; jc < 4; ++jc) {
          acc[jr][jc] += av[jr].x * wv[jc].x + av[jr].y * wv[jc].y +
                         av[jr].z * wv[jc].z + av[jr].w * wv[jc].w;
        }
    }
    __syncthreads();
  }

  float* sOut = sA;              // [64][68]
  float* sM = sA + 64 * 68;      // [64]
  float* sL = sM + 64;           // [64]
#pragma unroll
  for (int jr = 0; jr < 4; ++jr)
#pragma unroll
    for (int jc = 0; jc < 4; ++jc) {
      int r = tr * 4 + jr;
      int c = tc * 4 + jc;
      sOut[r * 68 + c] = acc[jr][jc] + b2[c];
    }
  __syncthreads();

  int w = t >> 6;
  int lane = t & 63;
  int row = w * 16 + (lane & 15);
  int cg = lane >> 4;
  float m = -1e30f;
  for (int j = 0; j < 16; ++j) m = fmaxf(m, sOut[row * 68 + cg * 16 + j]);
  m = fmaxf(m, __shfl_xor(m, 16));
  m = fmaxf(m, __shfl_xor(m, 32));
  float ssum = 0.f;
  for (int j = 0; j < 16; ++j) ssum += __expf(sOut[row * 68 + cg * 16 + j] - m);
  ssum += __shfl_xor(ssum, 16);
  ssum += __shfl_xor(ssum, 32);
  if (cg == 0) { sM[row] = m; sL[row] = __logf(ssum); }
  __syncthreads();

  int orow = t >> 2;
  int seg = t & 3;
  float mm = sM[orow];
  float ll = sL[orow];
#pragma unroll
  for (int j = 0; j < 4; ++j) {
    float4 v = *(float4*)&sOut[orow * 68 + seg * 16 + j * 4];
    float4 o = make_float4(v.x - mm - ll, v.y - mm - ll, v.z - mm - ll, v.w - mm - ll);
    ((float4*)(out + (size_t)(i0 + orow) * 64))[seg * 4 + j] = o;
  }
}

// ---------------- launch ----------------

extern "C" void kernel_launch(void* const* d_in, const int* in_sizes, int n_in,
                              void* d_out, int out_size, void* d_ws, size_t ws_size,
                              hipStream_t stream) {
  const float* x   = (const float*)d_in[0];
  const int* src1  = (const int*)d_in[1];
  const int* dst1  = (const int*)d_in[2];
  const int* src2  = (const int*)d_in[3];
  const int* dst2  = (const int*)d_in[4];
  const float* W1l = (const float*)d_in[5];
  const float* W1r = (const float*)d_in[6];
  const float* b1  = (const float*)d_in[7];
  const float* W2l = (const float*)d_in[8];
  const float* W2r = (const float*)d_in[9];
  const float* b2  = (const float*)d_in[10];
  float* out = (float*)d_out;

  float* ws = (float*)d_ws;
  float* aggr1 = ws;                                  // N1*128
  float* aggr2 = aggr1 + (size_t)N1C * 128;           // N2*256
  float* h1    = aggr2 + (size_t)N2C * 256;           // N1*256
  int* cnt1 = (int*)(h1 + (size_t)N1C * 256);         // N1
  int* cnt2 = cnt1 + N1C;                             // N2
  int* off1 = cnt2 + N2C;                             // N1
  int* off2 = off1 + N1C;                             // N2
  int* fill1 = off2 + N2C;                            // N1
  int* fill2 = fill1 + N1C;                           // N2
  int* bsum = fill2 + N2C;                            // 256
  int* ssrc1 = bsum + 256;                            // E1
  int* ssrc2 = ssrc1 + E1C;                           // E2

  // zero histograms (contiguous cnt1|cnt2)
  hipMemsetAsync(cnt1, 0, (size_t)(N1C + N2C) * sizeof(int), stream);

  // layer-1 CSR
  hist_kernel<<<E1C / 256, 256, 0, stream>>>(dst1, E1C, cnt1);
  scan1_kernel<<<N1C / 256, 256, 0, stream>>>(cnt1, off1, bsum);
  scan2_kernel<<<1, 256, 0, stream>>>(bsum, N1C / 256);
  scan3_kernel<<<N1C / 256, 256, 0, stream>>>(off1, bsum, fill1);
  sortedge_kernel<<<E1C / 256, 256, 0, stream>>>(src1, dst1, E1C, fill1, ssrc1);

  // layer-2 CSR (bsum reuse is safe: stream-ordered)
  hist_kernel<<<E2C / 256, 256, 0, stream>>>(dst2, E2C, cnt2);
  scan1_kernel<<<N2C / 256, 256, 0, stream>>>(cnt2, off2, bsum);
  scan2_kernel<<<1, 256, 0, stream>>>(bsum, N2C / 256);
  scan3_kernel<<<N2C / 256, 256, 0, stream>>>(off2, bsum, fill2);
  sortedge_kernel<<<E2C / 256, 256, 0, stream>>>(src2, dst2, E2C, fill2, ssrc2);

  // layer 1
  agg1_kernel<<<N1C / 4, 256, 0, stream>>>(x, ssrc1, off1, cnt1, aggr1);
  gemm1_kernel<<<dim3(N1C / 64, 4), 256, 0, stream>>>(aggr1, x, W1l, W1r, b1, h1);

  // layer 2
  agg2_kernel<<<N2C / 4, 256, 0, stream>>>(h1, ssrc2, off2, cnt2, aggr2);
  gemm2_kernel<<<N2C / 64, 256, 0, stream>>>(aggr2, h1, W2l, W2r, b2, out);
}

// Round 3
// 301.284 us; speedup vs baseline: 10.2062x; 1.6707x over previous
//
#include <hip/hip_runtime.h>
#include <cstdint>
#include <cstddef>

#define N0C 262144
#define N1C 65536
#define N2C 16384
#define E1C 1048576
#define E2C 262144
// IN_C=128, HID_C=256, OUT_C=64

typedef __attribute__((ext_vector_type(8))) short bf16x8;
typedef __attribute__((ext_vector_type(4))) float f32x4;

__device__ __forceinline__ unsigned short f2bf(float f) {
  union { float f; unsigned u; } q; q.f = f;
  unsigned r = q.u + 0x7fffu + ((q.u >> 16) & 1u);
  return (unsigned short)(r >> 16);
}
__device__ __forceinline__ float blo(unsigned u) {
  union { unsigned u; float f; } q; q.u = u << 16; return q.f;
}
__device__ __forceinline__ float bhi(unsigned u) {
  union { unsigned u; float f; } q; q.u = u & 0xffff0000u; return q.f;
}
__device__ __forceinline__ void gl_lds16(const void* g, void* l) {
  __builtin_amdgcn_global_load_lds((const __attribute__((address_space(1))) void*)g,
                                   (__attribute__((address_space(3))) void*)l, 16, 0, 0);
}

// ---------------- fp32 -> bf16 convert ----------------
__global__ void cvtbf16_kernel(const float4* __restrict__ in, ushort4* __restrict__ out, int n4) {
  int i = blockIdx.x * blockDim.x + threadIdx.x;
  int stride = gridDim.x * blockDim.x;
  for (; i < n4; i += stride) {
    float4 v = in[i];
    ushort4 o;
    o.x = f2bf(v.x); o.y = f2bf(v.y); o.z = f2bf(v.z); o.w = f2bf(v.w);
    out[i] = o;
  }
}

// ---------------- CSR build ----------------
__global__ void hist_kernel(const int* __restrict__ dst, int n, int* __restrict__ cnt) {
  int i = blockIdx.x * blockDim.x + threadIdx.x;
  if (i < n) atomicAdd(&cnt[dst[i]], 1);
}

__global__ __launch_bounds__(256) void scan1_kernel(const int* __restrict__ cnt,
                                                    int* __restrict__ excl,
                                                    int* __restrict__ bsum) {
  __shared__ int s[256];
  int t = threadIdx.x;
  int i = blockIdx.x * 256 + t;
  int v = cnt[i];
  s[t] = v;
  __syncthreads();
  for (int ofs = 1; ofs < 256; ofs <<= 1) {
    int add = (t >= ofs) ? s[t - ofs] : 0;
    __syncthreads();
    s[t] += add;
    __syncthreads();
  }
  excl[i] = s[t] - v;
  if (t == 255) bsum[blockIdx.x] = s[255];
}

__global__ __launch_bounds__(256) void scan2_kernel(int* __restrict__ bsum, int nb) {
  __shared__ int s[256];
  int t = threadIdx.x;
  int v = (t < nb) ? bsum[t] : 0;
  s[t] = v;
  __syncthreads();
  for (int ofs = 1; ofs < 256; ofs <<= 1) {
    int add = (t >= ofs) ? s[t - ofs] : 0;
    __syncthreads();
    s[t] += add;
    __syncthreads();
  }
  if (t < nb) bsum[t] = s[t] - v;
}

__global__ __launch_bounds__(256) void scan3_kernel(int* __restrict__ excl,
                                                    const int* __restrict__ bsum,
                                                    int* __restrict__ fill) {
  int i = blockIdx.x * 256 + threadIdx.x;
  int v = excl[i] + bsum[blockIdx.x];
  excl[i] = v;
  fill[i] = v;
}

__global__ void sortedge_kernel(const int* __restrict__ src, const int* __restrict__ dst,
                                int n, int* __restrict__ fill, int* __restrict__ ssrc) {
  int i = blockIdx.x * blockDim.x + threadIdx.x;
  if (i < n) {
    int d = dst[i];
    int pos = atomicAdd(&fill[d], 1);
    ssrc[pos] = src[i];
  }
}

// ---------------- gather aggregation (bf16 in, bf16 out, fp32 accum) ----------------

// layer 1: 128 ch; wave = 1 dst; halfwave (32 lanes) covers a row, 2 edges in parallel
__global__ __launch_bounds__(256) void agg1_kernel(const ushort* __restrict__ xb,
                                                   const int* __restrict__ ssrc,
                                                   const int* __restrict__ off,
                                                   const int* __restrict__ cnt,
                                                   ushort* __restrict__ aggr) {
  int wid = (blockIdx.x * 256 + threadIdx.x) >> 6;
  int lane = threadIdx.x & 63;
  int half = lane >> 5;
  int cl = lane & 31;
  int start = off[wid];
  int n = cnt[wid];
  float a0 = 0.f, a1 = 0.f, a2 = 0.f, a3 = 0.f;
  int j = 0;
  for (; j + 4 <= n; j += 4) {
    int sa = ssrc[start + j + half];
    int sb = ssrc[start + j + 2 + half];
    uint2 va = *(const uint2*)(xb + (size_t)sa * 128 + cl * 4);
    uint2 vb = *(const uint2*)(xb + (size_t)sb * 128 + cl * 4);
    a0 += blo(va.x) + blo(vb.x);
    a1 += bhi(va.x) + bhi(vb.x);
    a2 += blo(va.y) + blo(vb.y);
    a3 += bhi(va.y) + bhi(vb.y);
  }
  for (; j + 2 <= n; j += 2) {
    int s = ssrc[start + j + half];
    uint2 v = *(const uint2*)(xb + (size_t)s * 128 + cl * 4);
    a0 += blo(v.x); a1 += bhi(v.x); a2 += blo(v.y); a3 += bhi(v.y);
  }
  if ((n & 1) && half == 0) {
    int s = ssrc[start + n - 1];
    uint2 v = *(const uint2*)(xb + (size_t)s * 128 + cl * 4);
    a0 += blo(v.x); a1 += bhi(v.x); a2 += blo(v.y); a3 += bhi(v.y);
  }
  a0 += __shfl_xor(a0, 32);
  a1 += __shfl_xor(a1, 32);
  a2 += __shfl_xor(a2, 32);
  a3 += __shfl_xor(a3, 32);
  if (half == 0) {
    float inv = (n > 0) ? 1.0f / (float)n : 0.f;
    uint2 o;
    o.x = (unsigned)f2bf(a0 * inv) | ((unsigned)f2bf(a1 * inv) << 16);
    o.y = (unsigned)f2bf(a2 * inv) | ((unsigned)f2bf(a3 * inv) << 16);
    *(uint2*)(aggr + (size_t)wid * 128 + cl * 4) = o;
  }
}

// layer 2: 256 ch; wave = 1 dst; 64 lanes x 4 bf16 per row
__global__ __launch_bounds__(256) void agg2_kernel(const ushort* __restrict__ h1b,
                                                   const int* __restrict__ ssrc,
                                                   const int* __restrict__ off,
                                                   const int* __restrict__ cnt,
                                                   ushort* __restrict__ aggr) {
  int wid = (blockIdx.x * 256 + threadIdx.x) >> 6;
  int lane = threadIdx.x & 63;
  int start = off[wid];
  int n = cnt[wid];
  float a0 = 0.f, a1 = 0.f, a2 = 0.f, a3 = 0.f;
  int j = 0;
  for (; j + 2 <= n; j += 2) {
    int sa = ssrc[start + j];
    int sb = ssrc[start + j + 1];
    uint2 va = *(const uint2*)(h1b + (size_t)sa * 256 + lane * 4);
    uint2 vb = *(const uint2*)(h1b + (size_t)sb * 256 + lane * 4);
    a0 += blo(va.x) + blo(vb.x);
    a1 += bhi(va.x) + bhi(vb.x);
    a2 += blo(va.y) + blo(vb.y);
    a3 += bhi(va.y) + bhi(vb.y);
  }
  if (j < n) {
    int s = ssrc[start + j];
    uint2 v = *(const uint2*)(h1b + (size_t)s * 256 + lane * 4);
    a0 += blo(v.x); a1 += bhi(v.x); a2 += blo(v.y); a3 += bhi(v.y);
  }
  float inv = (n > 0) ? 1.0f / (float)n : 0.f;
  uint2 o;
  o.x = (unsigned)f2bf(a0 * inv) | ((unsigned)f2bf(a1 * inv) << 16);
  o.y = (unsigned)f2bf(a2 * inv) | ((unsigned)f2bf(a3 * inv) << 16);
  *(uint2*)(aggr + (size_t)wid * 256 + lane * 4) = o;
}

// ---------------- MFMA GEMM1: [N1,256] = relu([aggr1|x] @ [W1l|W1r]^T + b1), bf16 out
// 128x128 tile, 4 waves (2x2), each 64x64 = 4x4 frags of 16x16, BK=64, K=256 (4 tiles)
__global__ __launch_bounds__(256) void mgemm1_kernel(
    const ushort* __restrict__ aggr1, const ushort* __restrict__ xb,
    const ushort* __restrict__ W1lb, const ushort* __restrict__ W1rb,
    const float* __restrict__ b1, ushort* __restrict__ h1b) {
  __shared__ ushort sA[128 * 64];
  __shared__ ushort sB[128 * 64];
  int t = threadIdx.x;
  int lane = t & 63;
  int w = t >> 6;
  int wm = w >> 1, wn = w & 1;
  int i0 = blockIdx.x * 128;
  int c0 = blockIdx.y * 128;

  int sr = t >> 3;                 // staging row-in-group 0..31
  int sc = (t & 7) ^ (sr & 7);     // swizzled source chunk
  int quad = lane >> 4;
  int l15 = lane & 15;
  int xorv = lane & 7;

  f32x4 acc[4][4];
#pragma unroll
  for (int i = 0; i < 4; ++i)
#pragma unroll
    for (int j = 0; j < 4; ++j) acc[i][j] = (f32x4)(0.f);

  for (int kt = 0; kt < 4; ++kt) {
    const ushort* Asrc = (kt < 2) ? aggr1 : xb;
    const ushort* Bsrc = (kt < 2) ? W1lb : W1rb;
    int koff = (kt & 1) * 64;
#pragma unroll
    for (int it = 0; it < 4; ++it) {
      int r = it * 32 + sr;
      gl_lds16(Asrc + (size_t)(i0 + r) * 128 + koff + sc * 8, sA + (it * 256 + t) * 8);
    }
#pragma unroll
    for (int it = 0; it < 4; ++it) {
      int r = it * 32 + sr;
      gl_lds16(Bsrc + (size_t)(c0 + r) * 128 + koff + sc * 8, sB + (it * 256 + t) * 8);
    }
    __syncthreads();
#pragma unroll
    for (int s = 0; s < 2; ++s) {
      int chunk = ((s * 4 + quad) ^ xorv) * 8;
      bf16x8 av[4], bv[4];
#pragma unroll
      for (int fi = 0; fi < 4; ++fi)
        av[fi] = *(const bf16x8*)(sA + (wm * 64 + fi * 16 + l15) * 64 + chunk);
#pragma unroll
      for (int fj = 0; fj < 4; ++fj)
        bv[fj] = *(const bf16x8*)(sB + (wn * 64 + fj * 16 + l15) * 64 + chunk);
#pragma unroll
      for (int fi = 0; fi < 4; ++fi)
#pragma unroll
        for (int fj = 0; fj < 4; ++fj)
          acc[fi][fj] = __builtin_amdgcn_mfma_f32_16x16x32_bf16(av[fi], bv[fj], acc[fi][fj], 0, 0, 0);
    }
    __syncthreads();
  }

#pragma unroll
  for (int fj = 0; fj < 4; ++fj) {
    int c = c0 + wn * 64 + fj * 16 + l15;
    float bias = b1[c];
#pragma unroll
    for (int fi = 0; fi < 4; ++fi) {
#pragma unroll
      for (int r = 0; r < 4; ++r) {
        int m = i0 + wm * 64 + fi * 16 + quad * 4 + r;
        float v = fmaxf(acc[fi][fj][r] + bias, 0.f);
        h1b[(size_t)m * 256 + c] = f2bf(v);
      }
    }
  }
}

// ---------------- MFMA GEMM2 + bias + log_softmax: out[N2,64] fp32
// 64x64 tile, 4 waves each 16x64 (1x4 frags), BK=64, K=512 (8 tiles)
__global__ __launch_bounds__(256) void mgemm2_kernel(
    const ushort* __restrict__ aggr2, const ushort* __restrict__ h1b,
    const ushort* __restrict__ W2lb, const ushort* __restrict__ W2rb,
    const float* __restrict__ b2, float* __restrict__ out) {
  __shared__ ushort sA[64 * 64];
  __shared__ ushort sB[64 * 64];
  int t = threadIdx.x;
  int lane = t & 63;
  int w = t >> 6;
  int i0 = blockIdx.x * 64;

  int sr = t >> 3;
  int sc = (t & 7) ^ (sr & 7);
  int quad = lane >> 4;
  int l15 = lane & 15;
  int xorv = lane & 7;

  f32x4 acc[4];
#pragma unroll
  for (int j = 0; j < 4; ++j) acc[j] = (f32x4)(0.f);

  for (int kt = 0; kt < 8; ++kt) {
    const ushort* Asrc = (kt < 4) ? aggr2 : h1b;
    const ushort* Bsrc = (kt < 4) ? W2lb : W2rb;
    int koff = (kt & 3) * 64;
#pragma unroll
    for (int it = 0; it < 2; ++it) {
      int r = it * 32 + sr;
      gl_lds16(Asrc + (size_t)(i0 + r) * 256 + koff + sc * 8, sA + (it * 256 + t) * 8);
    }
#pragma unroll
    for (int it = 0; it < 2; ++it) {
      int r = it * 32 + sr;
      gl_lds16(Bsrc + (size_t)r * 256 + koff + sc * 8, sB + (it * 256 + t) * 8);
    }
    __syncthreads();
#pragma unroll
    for (int s = 0; s < 2; ++s) {
      int chunk = ((s * 4 + quad) ^ xorv) * 8;
      bf16x8 av = *(const bf16x8*)(sA + (w * 16 + l15) * 64 + chunk);
      bf16x8 bv[4];
#pragma unroll
      for (int fj = 0; fj < 4; ++fj)
        bv[fj] = *(const bf16x8*)(sB + (fj * 16 + l15) * 64 + chunk);
#pragma unroll
      for (int fj = 0; fj < 4; ++fj)
        acc[fj] = __builtin_amdgcn_mfma_f32_16x16x32_bf16(av, bv[fj], acc[fj], 0, 0, 0);
    }
    __syncthreads();
  }

  // epilogue: bias + per-row log_softmax via 16-lane shuffle reduce
  float b2c[4];
#pragma unroll
  for (int fj = 0; fj < 4; ++fj) b2c[fj] = b2[fj * 16 + l15];

#pragma unroll
  for (int r = 0; r < 4; ++r) {
    int row = i0 + w * 16 + quad * 4 + r;
    float v[4];
#pragma unroll
    for (int fj = 0; fj < 4; ++fj) v[fj] = acc[fj][r] + b2c[fj];
    float m = fmaxf(fmaxf(v[0], v[1]), fmaxf(v[2], v[3]));
    m = fmaxf(m, __shfl_xor(m, 1));
    m = fmaxf(m, __shfl_xor(m, 2));
    m = fmaxf(m, __shfl_xor(m, 4));
    m = fmaxf(m, __shfl_xor(m, 8));
    float ssum = __expf(v[0] - m) + __expf(v[1] - m) + __expf(v[2] - m) + __expf(v[3] - m);
    ssum += __shfl_xor(ssum, 1);
    ssum += __shfl_xor(ssum, 2);
    ssum += __shfl_xor(ssum, 4);
    ssum += __shfl_xor(ssum, 8);
    float lg = m + __logf(ssum);
#pragma unroll
    for (int fj = 0; fj < 4; ++fj)
      out[(size_t)row * 64 + fj * 16 + l15] = v[fj] - lg;
  }
}

// ---------------- launch ----------------

extern "C" void kernel_launch(void* const* d_in, const int* in_sizes, int n_in,
                              void* d_out, int out_size, void* d_ws, size_t ws_size,
                              hipStream_t stream) {
  const float* x   = (const float*)d_in[0];
  const int* src1  = (const int*)d_in[1];
  const int* dst1  = (const int*)d_in[2];
  const int* src2  = (const int*)d_in[3];
  const int* dst2  = (const int*)d_in[4];
  const float* W1l = (const float*)d_in[5];
  const float* W1r = (const float*)d_in[6];
  const float* b1  = (const float*)d_in[7];
  const float* W2l = (const float*)d_in[8];
  const float* W2r = (const float*)d_in[9];
  const float* b2  = (const float*)d_in[10];
  float* out = (float*)d_out;

  char* base = (char*)d_ws;
  ushort* xb   = (ushort*)base;                          // 33,554,432 ushorts (67.1 MB)
  ushort* h1b  = (ushort*)(base + 67108864);             // 16,777,216 ushorts (33.6 MB)
  ushort* ag1b = (ushort*)(base + 100663296);            // 8,388,608 ushorts (16.8 MB)
  int* cnt1  = (int*)(base + 117440512);                 // N1
  int* off1  = cnt1 + N1C;
  int* fill1 = off1 + N1C;
  int* cnt2  = fill1 + N1C;
  int* off2  = cnt2 + N2C;
  int* fill2 = off2 + N2C;
  int* bsum  = fill2 + N2C;                              // 1024 ints
  int* ssrc1 = bsum + 1024;                              // E1
  int* ssrc2 = ssrc1 + E1C;                              // E2
  // aliases (lifetime-disjoint):
  ushort* ag2b = xb;              // aggr2_bf16 (8.4 MB) after gemm1 is done with xb
  ushort* W1lb = (ushort*)ssrc1;  // weight bf16 (192 KB) after agg1 is done with ssrc1
  ushort* W1rb = W1lb + 32768;
  ushort* W2lb = W1rb + 32768;
  ushort* W2rb = W2lb + 16384;

  hipMemsetAsync(cnt1, 0, (size_t)N1C * sizeof(int), stream);
  hipMemsetAsync(cnt2, 0, (size_t)N2C * sizeof(int), stream);

  // convert x to bf16
  cvtbf16_kernel<<<4096, 256, 0, stream>>>((const float4*)x, (ushort4*)xb, N0C * 128 / 4);

  // CSR layer 1
  hist_kernel<<<E1C / 256, 256, 0, stream>>>(dst1, E1C, cnt1);
  scan1_kernel<<<N1C / 256, 256, 0, stream>>>(cnt1, off1, bsum);
  scan2_kernel<<<1, 256, 0, stream>>>(bsum, N1C / 256);
  scan3_kernel<<<N1C / 256, 256, 0, stream>>>(off1, bsum, fill1);
  sortedge_kernel<<<E1C / 256, 256, 0, stream>>>(src1, dst1, E1C, fill1, ssrc1);

  // CSR layer 2
  hist_kernel<<<E2C / 256, 256, 0, stream>>>(dst2, E2C, cnt2);
  scan1_kernel<<<N2C / 256, 256, 0, stream>>>(cnt2, off2, bsum);
  scan2_kernel<<<1, 256, 0, stream>>>(bsum, N2C / 256);
  scan3_kernel<<<N2C / 256, 256, 0, stream>>>(off2, bsum, fill2);
  sortedge_kernel<<<E2C / 256, 256, 0, stream>>>(src2, dst2, E2C, fill2, ssrc2);

  // layer 1 aggregate
  agg1_kernel<<<N1C / 4, 256, 0, stream>>>(xb, ssrc1, off1, cnt1, ag1b);

  // convert weights to bf16 (into ssrc1 space — agg1 done with it)
  cvtbf16_kernel<<<32, 256, 0, stream>>>((const float4*)W1l, (ushort4*)W1lb, 32768 / 4);
  cvtbf16_kernel<<<32, 256, 0, stream>>>((const float4*)W1r, (ushort4*)W1rb, 32768 / 4);
  cvtbf16_kernel<<<16, 256, 0, stream>>>((const float4*)W2l, (ushort4*)W2lb, 16384 / 4);
  cvtbf16_kernel<<<16, 256, 0, stream>>>((const float4*)W2r, (ushort4*)W2rb, 16384 / 4);

  // GEMM1 -> h1 bf16
  mgemm1_kernel<<<dim3(N1C / 128, 2), 256, 0, stream>>>(ag1b, xb, W1lb, W1rb, b1, h1b);

  // layer 2 aggregate (writes into xb space — gemm1 done with xb)
  agg2_kernel<<<N2C / 4, 256, 0, stream>>>(h1b, ssrc2, off2, cnt2, ag2b);

  // GEMM2 + log_softmax -> out fp32
  mgemm2_kernel<<<N2C / 64, 256, 0, stream>>>(ag2b, h1b, W2lb, W2rb, b2, out);
}

// Round 4
// 202.107 us; speedup vs baseline: 15.2146x; 1.4907x over previous
//
#include <hip/hip_runtime.h>
#include <cstdint>
#include <cstddef>

#define N0C 262144
#define N1C 65536
#define N2C 16384
#define E1C 1048576
#define E2C 262144
// IN_C=128, HID_C=256, OUT_C=64

typedef __attribute__((ext_vector_type(8))) short bf16x8;
typedef __attribute__((ext_vector_type(4))) float f32x4;

__device__ __forceinline__ unsigned short f2bf(float f) {
  union { float f; unsigned u; } q; q.f = f;
  unsigned r = q.u + 0x7fffu + ((q.u >> 16) & 1u);
  return (unsigned short)(r >> 16);
}
__device__ __forceinline__ float blo(unsigned u) {
  union { unsigned u; float f; } q; q.u = u << 16; return q.f;
}
__device__ __forceinline__ float bhi(unsigned u) {
  union { unsigned u; float f; } q; q.u = u & 0xffff0000u; return q.f;
}
__device__ __forceinline__ void gl_lds16(const void* g, void* l) {
  __builtin_amdgcn_global_load_lds((const __attribute__((address_space(1))) void*)g,
                                   (__attribute__((address_space(3))) void*)l, 16, 0, 0);
}

// ---------------- utility ----------------
__global__ void zero_kernel(int* __restrict__ p, int n) {
  int i = blockIdx.x * blockDim.x + threadIdx.x;
  if (i < n) p[i] = 0;
}

__global__ void cvtbf16_kernel(const float4* __restrict__ in, ushort4* __restrict__ out, int n4) {
  int i = blockIdx.x * blockDim.x + threadIdx.x;
  int stride = gridDim.x * blockDim.x;
  for (; i < n4; i += stride) {
    float4 v = in[i];
    ushort4 o;
    o.x = f2bf(v.x); o.y = f2bf(v.y); o.z = f2bf(v.z); o.w = f2bf(v.w);
    out[i] = o;
  }
}

// ---------------- binned counting sort (CSR build) ----------------
// Pass A: each block sorts 4096 edges into 256 coarse buckets (dst>>SHIFT) in LDS,
// reserves per-bucket global space, writes (src,dst) pairs in coalesced runs.
template<int SHIFT>
__global__ __launch_bounds__(256) void binA_kernel(const int* __restrict__ src,
                                                   const int* __restrict__ dst,
                                                   int* __restrict__ btail,
                                                   uint2* __restrict__ pairbuf) {
  __shared__ int hist[256];
  __shared__ int lofs[256];
  __shared__ int gbase[256];
  __shared__ int sstg[4096];
  __shared__ int dstg[4096];
  int t = threadIdx.x;
  int e0 = blockIdx.x * 4096;
  hist[t] = 0;
  __syncthreads();
  int s_[16], d_[16], rk[16];
#pragma unroll
  for (int k = 0; k < 16; ++k) {
    int e = e0 + k * 256 + t;
    s_[k] = src[e];
    d_[k] = dst[e];
    rk[k] = atomicAdd(&hist[d_[k] >> SHIFT], 1);
  }
  __syncthreads();
  int v = hist[t];
  lofs[t] = v;
  __syncthreads();
  for (int ofs = 1; ofs < 256; ofs <<= 1) {
    int add = (t >= ofs) ? lofs[t - ofs] : 0;
    __syncthreads();
    lofs[t] += add;
    __syncthreads();
  }
  gbase[t] = atomicAdd(&btail[t], v);    // one global atomic per bucket per block
  int excl = lofs[t] - v;
  lofs[t] = excl;
  __syncthreads();
#pragma unroll
  for (int k = 0; k < 16; ++k) {
    int p = lofs[d_[k] >> SHIFT] + rk[k];
    sstg[p] = s_[k];
    dstg[p] = d_[k];
  }
  __syncthreads();
  for (int i = t; i < 4096; i += 256) {
    int d = dstg[i];
    int bk = d >> SHIFT;
    int idx = gbase[bk] + (i - lofs[bk]);
    if (idx < 8192)
      pairbuf[(size_t)bk * 8192 + idx] = make_uint2((unsigned)sstg[i], (unsigned)d);
  }
}

// exclusive scan of 256 bucket tails per layer (blockIdx = layer)
__global__ __launch_bounds__(256) void scanB_kernel(const int* __restrict__ btail,
                                                    int* __restrict__ bbase) {
  __shared__ int s[256];
  int L = blockIdx.x;
  int t = threadIdx.x;
  int v = btail[L * 256 + t];
  s[t] = v;
  __syncthreads();
  for (int ofs = 1; ofs < 256; ofs <<= 1) {
    int add = (t >= ofs) ? s[t - ofs] : 0;
    __syncthreads();
    s[t] += add;
    __syncthreads();
  }
  bbase[L * 256 + t] = s[t] - v;
}

// Pass B: one block per bucket. Local hist + scan derives cnt/off, counting-sorts
// the bucket in LDS, streams ssrc out fully coalesced (bucket CSR range contiguous).
template<int DPB>   // dsts per bucket (256 for L1, 64 for L2)
__global__ __launch_bounds__(256) void binB_kernel(const uint2* __restrict__ pairbuf,
                                                   const int* __restrict__ btail,
                                                   const int* __restrict__ bbase,
                                                   int* __restrict__ off,
                                                   int* __restrict__ cnt,
                                                   int* __restrict__ ssrc) {
  __shared__ int lcnt[256];
  __shared__ int loff[256];
  __shared__ int lcnt2[256];
  __shared__ int stage[8192];
  int b = blockIdx.x;
  int t = threadIdx.x;
  int n = btail[b];
  if (n > 8192) n = 8192;
  int base = bbase[b];
  lcnt[t] = 0;
  lcnt2[t] = 0;
  __syncthreads();
  const uint2* pb = pairbuf + (size_t)b * 8192;
  for (int i = t; i < n; i += 256) {
    uint2 p = pb[i];
    atomicAdd(&lcnt[p.y & (DPB - 1)], 1);
  }
  __syncthreads();
  int v = lcnt[t];
  loff[t] = v;
  __syncthreads();
  for (int ofs = 1; ofs < 256; ofs <<= 1) {
    int add = (t >= ofs) ? loff[t - ofs] : 0;
    __syncthreads();
    loff[t] += add;
    __syncthreads();
  }
  int excl = loff[t] - v;
  loff[t] = excl;
  if (t < DPB) {
    cnt[b * DPB + t] = v;
    off[b * DPB + t] = base + excl;
  }
  __syncthreads();
  for (int i = t; i < n; i += 256) {
    uint2 p = pb[i];
    int dl = p.y & (DPB - 1);
    int r = atomicAdd(&lcnt2[dl], 1);
    stage[loff[dl] + r] = (int)p.x;
  }
  __syncthreads();
  for (int i = t; i < n; i += 256) ssrc[base + i] = stage[i];
}

// ---------------- gather aggregation (bf16 in, bf16 out, fp32 accum) ----------------

__global__ __launch_bounds__(256) void agg1_kernel(const ushort* __restrict__ xb,
                                                   const int* __restrict__ ssrc,
                                                   const int* __restrict__ off,
                                                   const int* __restrict__ cnt,
                                                   ushort* __restrict__ aggr) {
  int wid = (blockIdx.x * 256 + threadIdx.x) >> 6;
  int lane = threadIdx.x & 63;
  int half = lane >> 5;
  int cl = lane & 31;
  int start = off[wid];
  int n = cnt[wid];
  float a0 = 0.f, a1 = 0.f, a2 = 0.f, a3 = 0.f;
  int j = 0;
  for (; j + 4 <= n; j += 4) {
    int sa = ssrc[start + j + half];
    int sb = ssrc[start + j + 2 + half];
    uint2 va = *(const uint2*)(xb + (size_t)sa * 128 + cl * 4);
    uint2 vb = *(const uint2*)(xb + (size_t)sb * 128 + cl * 4);
    a0 += blo(va.x) + blo(vb.x);
    a1 += bhi(va.x) + bhi(vb.x);
    a2 += blo(va.y) + blo(vb.y);
    a3 += bhi(va.y) + bhi(vb.y);
  }
  for (; j + 2 <= n; j += 2) {
    int s = ssrc[start + j + half];
    uint2 v = *(const uint2*)(xb + (size_t)s * 128 + cl * 4);
    a0 += blo(v.x); a1 += bhi(v.x); a2 += blo(v.y); a3 += bhi(v.y);
  }
  if ((n & 1) && half == 0) {
    int s = ssrc[start + n - 1];
    uint2 v = *(const uint2*)(xb + (size_t)s * 128 + cl * 4);
    a0 += blo(v.x); a1 += bhi(v.x); a2 += blo(v.y); a3 += bhi(v.y);
  }
  a0 += __shfl_xor(a0, 32);
  a1 += __shfl_xor(a1, 32);
  a2 += __shfl_xor(a2, 32);
  a3 += __shfl_xor(a3, 32);
  if (half == 0) {
    float inv = (n > 0) ? 1.0f / (float)n : 0.f;
    uint2 o;
    o.x = (unsigned)f2bf(a0 * inv) | ((unsigned)f2bf(a1 * inv) << 16);
    o.y = (unsigned)f2bf(a2 * inv) | ((unsigned)f2bf(a3 * inv) << 16);
    *(uint2*)(aggr + (size_t)wid * 128 + cl * 4) = o;
  }
}

__global__ __launch_bounds__(256) void agg2_kernel(const ushort* __restrict__ h1b,
                                                   const int* __restrict__ ssrc,
                                                   const int* __restrict__ off,
                                                   const int* __restrict__ cnt,
                                                   ushort* __restrict__ aggr) {
  int wid = (blockIdx.x * 256 + threadIdx.x) >> 6;
  int lane = threadIdx.x & 63;
  int start = off[wid];
  int n = cnt[wid];
  float a0 = 0.f, a1 = 0.f, a2 = 0.f, a3 = 0.f;
  int j = 0;
  for (; j + 2 <= n; j += 2) {
    int sa = ssrc[start + j];
    int sb = ssrc[start + j + 1];
    uint2 va = *(const uint2*)(h1b + (size_t)sa * 256 + lane * 4);
    uint2 vb = *(const uint2*)(h1b + (size_t)sb * 256 + lane * 4);
    a0 += blo(va.x) + blo(vb.x);
    a1 += bhi(va.x) + bhi(vb.x);
    a2 += blo(va.y) + blo(vb.y);
    a3 += bhi(va.y) + bhi(vb.y);
  }
  if (j < n) {
    int s = ssrc[start + j];
    uint2 v = *(const uint2*)(h1b + (size_t)s * 256 + lane * 4);
    a0 += blo(v.x); a1 += bhi(v.x); a2 += blo(v.y); a3 += bhi(v.y);
  }
  float inv = (n > 0) ? 1.0f / (float)n : 0.f;
  uint2 o;
  o.x = (unsigned)f2bf(a0 * inv) | ((unsigned)f2bf(a1 * inv) << 16);
  o.y = (unsigned)f2bf(a2 * inv) | ((unsigned)f2bf(a3 * inv) << 16);
  *(uint2*)(aggr + (size_t)wid * 256 + lane * 4) = o;
}

// ---------------- MFMA GEMM1: [N1,256] = relu([aggr1|x] @ [W1l|W1r]^T + b1), bf16 out
__global__ __launch_bounds__(256) void mgemm1_kernel(
    const ushort* __restrict__ aggr1, const ushort* __restrict__ xb,
    const ushort* __restrict__ W1lb, const ushort* __restrict__ W1rb,
    const float* __restrict__ b1, ushort* __restrict__ h1b) {
  __shared__ ushort sA[128 * 64];
  __shared__ ushort sB[128 * 64];
  int t = threadIdx.x;
  int lane = t & 63;
  int w = t >> 6;
  int wm = w >> 1, wn = w & 1;
  int i0 = blockIdx.x * 128;
  int c0 = blockIdx.y * 128;

  int sr = t >> 3;
  int sc = (t & 7) ^ (sr & 7);
  int quad = lane >> 4;
  int l15 = lane & 15;
  int xorv = lane & 7;

  f32x4 acc[4][4];
#pragma unroll
  for (int i = 0; i < 4; ++i)
#pragma unroll
    for (int j = 0; j < 4; ++j) acc[i][j] = (f32x4)(0.f);

  for (int kt = 0; kt < 4; ++kt) {
    const ushort* Asrc = (kt < 2) ? aggr1 : xb;
    const ushort* Bsrc = (kt < 2) ? W1lb : W1rb;
    int koff = (kt & 1) * 64;
#pragma unroll
    for (int it = 0; it < 4; ++it) {
      int r = it * 32 + sr;
      gl_lds16(Asrc + (size_t)(i0 + r) * 128 + koff + sc * 8, sA + (it * 256 + t) * 8);
    }
#pragma unroll
    for (int it = 0; it < 4; ++it) {
      int r = it * 32 + sr;
      gl_lds16(Bsrc + (size_t)(c0 + r) * 128 + koff + sc * 8, sB + (it * 256 + t) * 8);
    }
    __syncthreads();
#pragma unroll
    for (int s = 0; s < 2; ++s) {
      int chunk = ((s * 4 + quad) ^ xorv) * 8;
      bf16x8 av[4], bv[4];
#pragma unroll
      for (int fi = 0; fi < 4; ++fi)
        av[fi] = *(const bf16x8*)(sA + (wm * 64 + fi * 16 + l15) * 64 + chunk);
#pragma unroll
      for (int fj = 0; fj < 4; ++fj)
        bv[fj] = *(const bf16x8*)(sB + (wn * 64 + fj * 16 + l15) * 64 + chunk);
#pragma unroll
      for (int fi = 0; fi < 4; ++fi)
#pragma unroll
        for (int fj = 0; fj < 4; ++fj)
          acc[fi][fj] = __builtin_amdgcn_mfma_f32_16x16x32_bf16(av[fi], bv[fj], acc[fi][fj], 0, 0, 0);
    }
    __syncthreads();
  }

#pragma unroll
  for (int fj = 0; fj < 4; ++fj) {
    int c = c0 + wn * 64 + fj * 16 + l15;
    float bias = b1[c];
#pragma unroll
    for (int fi = 0; fi < 4; ++fi) {
#pragma unroll
      for (int r = 0; r < 4; ++r) {
        int m = i0 + wm * 64 + fi * 16 + quad * 4 + r;
        float v = fmaxf(acc[fi][fj][r] + bias, 0.f);
        h1b[(size_t)m * 256 + c] = f2bf(v);
      }
    }
  }
}

// ---------------- MFMA GEMM2 + bias + log_softmax: out[N2,64] fp32
__global__ __launch_bounds__(256) void mgemm2_kernel(
    const ushort* __restrict__ aggr2, const ushort* __restrict__ h1b,
    const ushort* __restrict__ W2lb, const ushort* __restrict__ W2rb,
    const float* __restrict__ b2, float* __restrict__ out) {
  __shared__ ushort sA[64 * 64];
  __shared__ ushort sB[64 * 64];
  int t = threadIdx.x;
  int lane = t & 63;
  int w = t >> 6;
  int i0 = blockIdx.x * 64;

  int sr = t >> 3;
  int sc = (t & 7) ^ (sr & 7);
  int quad = lane >> 4;
  int l15 = lane & 15;
  int xorv = lane & 7;

  f32x4 acc[4];
#pragma unroll
  for (int j = 0; j < 4; ++j) acc[j] = (f32x4)(0.f);

  for (int kt = 0; kt < 8; ++kt) {
    const ushort* Asrc = (kt < 4) ? aggr2 : h1b;
    const ushort* Bsrc = (kt < 4) ? W2lb : W2rb;
    int koff = (kt & 3) * 64;
#pragma unroll
    for (int it = 0; it < 2; ++it) {
      int r = it * 32 + sr;
      gl_lds16(Asrc + (size_t)(i0 + r) * 256 + koff + sc * 8, sA + (it * 256 + t) * 8);
    }
#pragma unroll
    for (int it = 0; it < 2; ++it) {
      int r = it * 32 + sr;
      gl_lds16(Bsrc + (size_t)r * 256 + koff + sc * 8, sB + (it * 256 + t) * 8);
    }
    __syncthreads();
#pragma unroll
    for (int s = 0; s < 2; ++s) {
      int chunk = ((s * 4 + quad) ^ xorv) * 8;
      bf16x8 av = *(const bf16x8*)(sA + (w * 16 + l15) * 64 + chunk);
      bf16x8 bv[4];
#pragma unroll
      for (int fj = 0; fj < 4; ++fj)
        bv[fj] = *(const bf16x8*)(sB + (fj * 16 + l15) * 64 + chunk);
#pragma unroll
      for (int fj = 0; fj < 4; ++fj)
        acc[fj] = __builtin_amdgcn_mfma_f32_16x16x32_bf16(av, bv[fj], acc[fj], 0, 0, 0);
    }
    __syncthreads();
  }

  float b2c[4];
#pragma unroll
  for (int fj = 0; fj < 4; ++fj) b2c[fj] = b2[fj * 16 + l15];

#pragma unroll
  for (int r = 0; r < 4; ++r) {
    int row = i0 + w * 16 + quad * 4 + r;
    float v[4];
#pragma unroll
    for (int fj = 0; fj < 4; ++fj) v[fj] = acc[fj][r] + b2c[fj];
    float m = fmaxf(fmaxf(v[0], v[1]), fmaxf(v[2], v[3]));
    m = fmaxf(m, __shfl_xor(m, 1));
    m = fmaxf(m, __shfl_xor(m, 2));
    m = fmaxf(m, __shfl_xor(m, 4));
    m = fmaxf(m, __shfl_xor(m, 8));
    float ssum = __expf(v[0] - m) + __expf(v[1] - m) + __expf(v[2] - m) + __expf(v[3] - m);
    ssum += __shfl_xor(ssum, 1);
    ssum += __shfl_xor(ssum, 2);
    ssum += __shfl_xor(ssum, 4);
    ssum += __shfl_xor(ssum, 8);
    float lg = m + __logf(ssum);
#pragma unroll
    for (int fj = 0; fj < 4; ++fj)
      out[(size_t)row * 64 + fj * 16 + l15] = v[fj] - lg;
  }
}

// ---------------- launch ----------------

extern "C" void kernel_launch(void* const* d_in, const int* in_sizes, int n_in,
                              void* d_out, int out_size, void* d_ws, size_t ws_size,
                              hipStream_t stream) {
  const float* x   = (const float*)d_in[0];
  const int* src1  = (const int*)d_in[1];
  const int* dst1  = (const int*)d_in[2];
  const int* src2  = (const int*)d_in[3];
  const int* dst2  = (const int*)d_in[4];
  const float* W1l = (const float*)d_in[5];
  const float* W1r = (const float*)d_in[6];
  const float* b1  = (const float*)d_in[7];
  const float* W2l = (const float*)d_in[8];
  const float* W2r = (const float*)d_in[9];
  const float* b2  = (const float*)d_in[10];
  float* out = (float*)d_out;

  char* base = (char*)d_ws;
  ushort* xb   = (ushort*)base;                          // 67.1 MB
  ushort* h1b  = (ushort*)(base + 67108864);             // 33.6 MB
  ushort* ag1b = (ushort*)(base + 100663296);            // 16.8 MB
  uint2* pair1 = (uint2*)(base + 117440512);             // 256*8192*8 = 16.8 MB
  uint2* pair2 = (uint2*)(base + 134217728);             // 16.8 MB
  int* cnt1  = (int*)(base + 150994944);                 // N1
  int* off1  = cnt1 + N1C;                               // N1
  int* cnt2  = off1 + N1C;                               // N2
  int* off2  = cnt2 + N2C;                               // N2
  int* btail = off2 + N2C;                               // 512 (2 layers x 256)
  int* bbase = btail + 512;                              // 512
  int* ssrc1 = bbase + 512;                              // E1
  int* ssrc2 = ssrc1 + E1C;                              // E2
  ushort* W1lb = (ushort*)(ssrc2 + E2C);                 // 32768
  ushort* W1rb = W1lb + 32768;
  ushort* W2lb = W1rb + 32768;
  ushort* W2rb = W2lb + 16384;
  ushort* ag2b = xb;   // alias: aggr2 written after mgemm1's last read of xb

  // zero bucket tails (512 ints)
  zero_kernel<<<2, 256, 0, stream>>>(btail, 512);

  // convert x + weights to bf16
  cvtbf16_kernel<<<4096, 256, 0, stream>>>((const float4*)x, (ushort4*)xb, N0C * 128 / 4);
  cvtbf16_kernel<<<32, 256, 0, stream>>>((const float4*)W1l, (ushort4*)W1lb, 32768 / 4);
  cvtbf16_kernel<<<32, 256, 0, stream>>>((const float4*)W1r, (ushort4*)W1rb, 32768 / 4);
  cvtbf16_kernel<<<16, 256, 0, stream>>>((const float4*)W2l, (ushort4*)W2lb, 16384 / 4);
  cvtbf16_kernel<<<16, 256, 0, stream>>>((const float4*)W2r, (ushort4*)W2rb, 16384 / 4);

  // CSR build, both layers (binned 2-pass counting sort; Pass B emits cnt/off too)
  binA_kernel<8><<<E1C / 4096, 256, 0, stream>>>(src1, dst1, btail, pair1);
  binA_kernel<6><<<E2C / 4096, 256, 0, stream>>>(src2, dst2, btail + 256, pair2);
  scanB_kernel<<<2, 256, 0, stream>>>(btail, bbase);
  binB_kernel<256><<<256, 256, 0, stream>>>(pair1, btail, bbase, off1, cnt1, ssrc1);
  binB_kernel<64><<<256, 256, 0, stream>>>(pair2, btail + 256, bbase + 256, off2, cnt2, ssrc2);

  // layer 1
  agg1_kernel<<<N1C / 4, 256, 0, stream>>>(xb, ssrc1, off1, cnt1, ag1b);
  mgemm1_kernel<<<dim3(N1C / 128, 2), 256, 0, stream>>>(ag1b, xb, W1lb, W1rb, b1, h1b);

  // layer 2
  agg2_kernel<<<N2C / 4, 256, 0, stream>>>(h1b, ssrc2, off2, cnt2, ag2b);
  mgemm2_kernel<<<N2C / 64, 256, 0, stream>>>(ag2b, h1b, W2lb, W2rb, b2, out);
}

// Round 5
// 184.053 us; speedup vs baseline: 16.7070x; 1.0981x over previous
//
#include <hip/hip_runtime.h>
#include <cstdint>
#include <cstddef>

#define N0C 262144
#define N1C 65536
#define N2C 16384
#define E1C 1048576
#define E2C 262144
// IN_C=128, HID_C=256, OUT_C=64

typedef __attribute__((ext_vector_type(8))) short bf16x8;
typedef __attribute__((ext_vector_type(4))) float f32x4;

__device__ __forceinline__ unsigned short f2bf(float f) {
  union { float f; unsigned u; } q; q.f = f;
  unsigned r = q.u + 0x7fffu + ((q.u >> 16) & 1u);
  return (unsigned short)(r >> 16);
}
__device__ __forceinline__ float blo(unsigned u) {
  union { unsigned u; float f; } q; q.u = u << 16; return q.f;
}
__device__ __forceinline__ float bhi(unsigned u) {
  union { unsigned u; float f; } q; q.u = u & 0xffff0000u; return q.f;
}
__device__ __forceinline__ void gl_lds16(const void* g, void* l) {
  __builtin_amdgcn_global_load_lds((const __attribute__((address_space(1))) void*)g,
                                   (__attribute__((address_space(3))) void*)l, 16, 0, 0);
}

// ---------------- fp32 -> bf16 conversions ----------------
__global__ void cvtbf16_kernel(const float4* __restrict__ in, ushort4* __restrict__ out, int n4) {
  int i = blockIdx.x * blockDim.x + threadIdx.x;
  int stride = gridDim.x * blockDim.x;
  for (; i < n4; i += stride) {
    float4 v = in[i];
    ushort4 o;
    o.x = f2bf(v.x); o.y = f2bf(v.y); o.z = f2bf(v.z); o.w = f2bf(v.w);
    out[i] = o;
  }
}

// fused: 4 weight tensors -> bf16, plus btail zeroing (blockIdx.y selects)
__global__ __launch_bounds__(256) void cvtw_kernel(
    const float4* __restrict__ W1l, const float4* __restrict__ W1r,
    const float4* __restrict__ W2l, const float4* __restrict__ W2r,
    ushort4* __restrict__ W1lb, ushort4* __restrict__ W1rb,
    ushort4* __restrict__ W2lb, ushort4* __restrict__ W2rb,
    int* __restrict__ btail) {
  int y = blockIdx.y;
  int i = blockIdx.x * 256 + threadIdx.x;
  if (y == 4) {
    if (i < 512) btail[i] = 0;
    return;
  }
  const float4* in; ushort4* outp; int n4;
  if (y == 0)      { in = W1l; outp = W1lb; n4 = 8192; }
  else if (y == 1) { in = W1r; outp = W1rb; n4 = 8192; }
  else if (y == 2) { in = W2l; outp = W2lb; n4 = 4096; }
  else             { in = W2r; outp = W2rb; n4 = 4096; }
  if (i < n4) {
    float4 v = in[i];
    ushort4 o;
    o.x = f2bf(v.x); o.y = f2bf(v.y); o.z = f2bf(v.z); o.w = f2bf(v.w);
    outp[i] = o;
  }
}

// ---------------- binned counting sort (CSR build) ----------------
template<int SHIFT>
__global__ __launch_bounds__(256) void binA_kernel(const int* __restrict__ src,
                                                   const int* __restrict__ dst,
                                                   int* __restrict__ btail,
                                                   uint2* __restrict__ pairbuf) {
  __shared__ int hist[256];
  __shared__ int lofs[256];
  __shared__ int gbase[256];
  __shared__ int sstg[4096];
  __shared__ int dstg[4096];
  int t = threadIdx.x;
  int e0 = blockIdx.x * 4096;
  hist[t] = 0;
  __syncthreads();
  int s_[16], d_[16], rk[16];
#pragma unroll
  for (int k = 0; k < 16; ++k) {
    int e = e0 + k * 256 + t;
    s_[k] = src[e];
    d_[k] = dst[e];
    rk[k] = atomicAdd(&hist[d_[k] >> SHIFT], 1);
  }
  __syncthreads();
  int v = hist[t];
  lofs[t] = v;
  __syncthreads();
  for (int ofs = 1; ofs < 256; ofs <<= 1) {
    int add = (t >= ofs) ? lofs[t - ofs] : 0;
    __syncthreads();
    lofs[t] += add;
    __syncthreads();
  }
  gbase[t] = atomicAdd(&btail[t], v);
  int excl = lofs[t] - v;
  lofs[t] = excl;
  __syncthreads();
#pragma unroll
  for (int k = 0; k < 16; ++k) {
    int p = lofs[d_[k] >> SHIFT] + rk[k];
    sstg[p] = s_[k];
    dstg[p] = d_[k];
  }
  __syncthreads();
  for (int i = t; i < 4096; i += 256) {
    int d = dstg[i];
    int bk = d >> SHIFT;
    int idx = gbase[bk] + (i - lofs[bk]);
    if (idx < 8192)
      pairbuf[(size_t)bk * 8192 + idx] = make_uint2((unsigned)sstg[i], (unsigned)d);
  }
}

__global__ __launch_bounds__(256) void scanB_kernel(const int* __restrict__ btail,
                                                    int* __restrict__ bbase) {
  __shared__ int s[256];
  int L = blockIdx.x;
  int t = threadIdx.x;
  int v = btail[L * 256 + t];
  s[t] = v;
  __syncthreads();
  for (int ofs = 1; ofs < 256; ofs <<= 1) {
    int add = (t >= ofs) ? s[t - ofs] : 0;
    __syncthreads();
    s[t] += add;
    __syncthreads();
  }
  bbase[L * 256 + t] = s[t] - v;
}

template<int DPB>
__global__ __launch_bounds__(256) void binB_kernel(const uint2* __restrict__ pairbuf,
                                                   const int* __restrict__ btail,
                                                   const int* __restrict__ bbase,
                                                   int* __restrict__ off,
                                                   int* __restrict__ cnt,
                                                   int* __restrict__ ssrc) {
  __shared__ int lcnt[256];
  __shared__ int loff[256];
  __shared__ int lcnt2[256];
  __shared__ int stage[8192];
  int b = blockIdx.x;
  int t = threadIdx.x;
  int n = btail[b];
  if (n > 8192) n = 8192;
  int base = bbase[b];
  lcnt[t] = 0;
  lcnt2[t] = 0;
  __syncthreads();
  const uint2* pb = pairbuf + (size_t)b * 8192;
  for (int i = t; i < n; i += 256) {
    uint2 p = pb[i];
    atomicAdd(&lcnt[p.y & (DPB - 1)], 1);
  }
  __syncthreads();
  int v = lcnt[t];
  loff[t] = v;
  __syncthreads();
  for (int ofs = 1; ofs < 256; ofs <<= 1) {
    int add = (t >= ofs) ? loff[t - ofs] : 0;
    __syncthreads();
    loff[t] += add;
    __syncthreads();
  }
  int excl = loff[t] - v;
  loff[t] = excl;
  if (t < DPB) {
    cnt[b * DPB + t] = v;
    off[b * DPB + t] = base + excl;
  }
  __syncthreads();
  for (int i = t; i < n; i += 256) {
    uint2 p = pb[i];
    int dl = p.y & (DPB - 1);
    int r = atomicAdd(&lcnt2[dl], 1);
    stage[loff[dl] + r] = (int)p.x;
  }
  __syncthreads();
  for (int i = t; i < n; i += 256) ssrc[base + i] = stage[i];
}

// ---------------- gather aggregation (bf16 in, bf16 out, fp32 accum) ----------------

// layer 1: 128 ch = 256B bf16 row = 16 lanes x uint4; 4 edges in flight per wave
__global__ __launch_bounds__(256) void agg1_kernel(const ushort* __restrict__ xb,
                                                   const int* __restrict__ ssrc,
                                                   const int* __restrict__ off,
                                                   const int* __restrict__ cnt,
                                                   ushort* __restrict__ aggr) {
  int wid = (blockIdx.x * 256 + threadIdx.x) >> 6;
  int lane = threadIdx.x & 63;
  int grp = lane >> 4;
  int cl = lane & 15;
  int start = __builtin_amdgcn_readfirstlane(off[wid]);
  int n = __builtin_amdgcn_readfirstlane(cnt[wid]);
  float a0 = 0.f, a1 = 0.f, a2 = 0.f, a3 = 0.f, a4 = 0.f, a5 = 0.f, a6 = 0.f, a7 = 0.f;
  int j = 0;
  for (; j + 4 <= n; j += 4) {
    int s = ssrc[start + j + grp];
    uint4 v = *(const uint4*)(xb + (size_t)s * 128 + cl * 8);
    a0 += blo(v.x); a1 += bhi(v.x); a2 += blo(v.y); a3 += bhi(v.y);
    a4 += blo(v.z); a5 += bhi(v.z); a6 += blo(v.w); a7 += bhi(v.w);
  }
  int rem = n - j;
  if (grp < rem) {
    int s = ssrc[start + j + grp];
    uint4 v = *(const uint4*)(xb + (size_t)s * 128 + cl * 8);
    a0 += blo(v.x); a1 += bhi(v.x); a2 += blo(v.y); a3 += bhi(v.y);
    a4 += blo(v.z); a5 += bhi(v.z); a6 += blo(v.w); a7 += bhi(v.w);
  }
#define RED1(x) x += __shfl_xor(x, 16); x += __shfl_xor(x, 32);
  RED1(a0) RED1(a1) RED1(a2) RED1(a3) RED1(a4) RED1(a5) RED1(a6) RED1(a7)
#undef RED1
  if (lane < 16) {
    float inv = (n > 0) ? 1.0f / (float)n : 0.f;
    uint4 o;
    o.x = (unsigned)f2bf(a0 * inv) | ((unsigned)f2bf(a1 * inv) << 16);
    o.y = (unsigned)f2bf(a2 * inv) | ((unsigned)f2bf(a3 * inv) << 16);
    o.z = (unsigned)f2bf(a4 * inv) | ((unsigned)f2bf(a5 * inv) << 16);
    o.w = (unsigned)f2bf(a6 * inv) | ((unsigned)f2bf(a7 * inv) << 16);
    *(uint4*)(aggr + (size_t)wid * 128 + cl * 8) = o;
  }
}

// layer 2: 256 ch = 512B bf16 row = 32 lanes x uint4; 2 slots x 2-deep unroll
__global__ __launch_bounds__(256) void agg2_kernel(const ushort* __restrict__ h1b,
                                                   const int* __restrict__ ssrc,
                                                   const int* __restrict__ off,
                                                   const int* __restrict__ cnt,
                                                   ushort* __restrict__ aggr) {
  int wid = (blockIdx.x * 256 + threadIdx.x) >> 6;
  int lane = threadIdx.x & 63;
  int grp = lane >> 5;
  int cl = lane & 31;
  int start = __builtin_amdgcn_readfirstlane(off[wid]);
  int n = __builtin_amdgcn_readfirstlane(cnt[wid]);
  float a0 = 0.f, a1 = 0.f, a2 = 0.f, a3 = 0.f, a4 = 0.f, a5 = 0.f, a6 = 0.f, a7 = 0.f;
  int j = 0;
  for (; j + 4 <= n; j += 4) {
    int sa = ssrc[start + j + grp];
    int sb = ssrc[start + j + 2 + grp];
    uint4 va = *(const uint4*)(h1b + (size_t)sa * 256 + cl * 8);
    uint4 vb = *(const uint4*)(h1b + (size_t)sb * 256 + cl * 8);
    a0 += blo(va.x) + blo(vb.x); a1 += bhi(va.x) + bhi(vb.x);
    a2 += blo(va.y) + blo(vb.y); a3 += bhi(va.y) + bhi(vb.y);
    a4 += blo(va.z) + blo(vb.z); a5 += bhi(va.z) + bhi(vb.z);
    a6 += blo(va.w) + blo(vb.w); a7 += bhi(va.w) + bhi(vb.w);
  }
  if (j + 2 <= n) {
    int s = ssrc[start + j + grp];
    uint4 v = *(const uint4*)(h1b + (size_t)s * 256 + cl * 8);
    a0 += blo(v.x); a1 += bhi(v.x); a2 += blo(v.y); a3 += bhi(v.y);
    a4 += blo(v.z); a5 += bhi(v.z); a6 += blo(v.w); a7 += bhi(v.w);
    j += 2;
  }
  if (grp < n - j) {
    int s = ssrc[start + j + grp];
    uint4 v = *(const uint4*)(h1b + (size_t)s * 256 + cl * 8);
    a0 += blo(v.x); a1 += bhi(v.x); a2 += blo(v.y); a3 += bhi(v.y);
    a4 += blo(v.z); a5 += bhi(v.z); a6 += blo(v.w); a7 += bhi(v.w);
  }
#define RED2(x) x += __shfl_xor(x, 32);
  RED2(a0) RED2(a1) RED2(a2) RED2(a3) RED2(a4) RED2(a5) RED2(a6) RED2(a7)
#undef RED2
  if (lane < 32) {
    float inv = (n > 0) ? 1.0f / (float)n : 0.f;
    uint4 o;
    o.x = (unsigned)f2bf(a0 * inv) | ((unsigned)f2bf(a1 * inv) << 16);
    o.y = (unsigned)f2bf(a2 * inv) | ((unsigned)f2bf(a3 * inv) << 16);
    o.z = (unsigned)f2bf(a4 * inv) | ((unsigned)f2bf(a5 * inv) << 16);
    o.w = (unsigned)f2bf(a6 * inv) | ((unsigned)f2bf(a7 * inv) << 16);
    *(uint4*)(aggr + (size_t)wid * 256 + cl * 8) = o;
  }
}

// ---------------- MFMA GEMM1: [N1,256] = relu([aggr1|x] @ [W1l|W1r]^T + b1), bf16 out
// 128x128 tile, 4 waves (2x2), each 64x64 = 4x4 frags of 16x16, BK=64, K=256 (4 tiles)
// Epilogue: per-wave-private LDS staging -> coalesced uint2 (4 bf16) stores.
__global__ __launch_bounds__(256) void mgemm1_kernel(
    const ushort* __restrict__ aggr1, const ushort* __restrict__ xb,
    const ushort* __restrict__ W1lb, const ushort* __restrict__ W1rb,
    const float* __restrict__ b1, ushort* __restrict__ h1b) {
  __shared__ ushort smem[2 * 128 * 64];
  ushort* sA = smem;
  ushort* sB = smem + 128 * 64;
  int t = threadIdx.x;
  int lane = t & 63;
  int w = t >> 6;
  int wm = w >> 1, wn = w & 1;
  int i0 = blockIdx.x * 128;
  int c0 = blockIdx.y * 128;

  int sr = t >> 3;
  int sc = (t & 7) ^ (sr & 7);
  int quad = lane >> 4;
  int l15 = lane & 15;
  int xorv = lane & 7;

  f32x4 acc[4][4];
#pragma unroll
  for (int i = 0; i < 4; ++i)
#pragma unroll
    for (int j = 0; j < 4; ++j) acc[i][j] = (f32x4)(0.f);

  for (int kt = 0; kt < 4; ++kt) {
    const ushort* Asrc = (kt < 2) ? aggr1 : xb;
    const ushort* Bsrc = (kt < 2) ? W1lb : W1rb;
    int koff = (kt & 1) * 64;
#pragma unroll
    for (int it = 0; it < 4; ++it) {
      int r = it * 32 + sr;
      gl_lds16(Asrc + (size_t)(i0 + r) * 128 + koff + sc * 8, sA + (it * 256 + t) * 8);
    }
#pragma unroll
    for (int it = 0; it < 4; ++it) {
      int r = it * 32 + sr;
      gl_lds16(Bsrc + (size_t)(c0 + r) * 128 + koff + sc * 8, sB + (it * 256 + t) * 8);
    }
    __syncthreads();
#pragma unroll
    for (int s = 0; s < 2; ++s) {
      int chunk = ((s * 4 + quad) ^ xorv) * 8;
      bf16x8 av[4], bv[4];
#pragma unroll
      for (int fi = 0; fi < 4; ++fi)
        av[fi] = *(const bf16x8*)(sA + (wm * 64 + fi * 16 + l15) * 64 + chunk);
#pragma unroll
      for (int fj = 0; fj < 4; ++fj)
        bv[fj] = *(const bf16x8*)(sB + (wn * 64 + fj * 16 + l15) * 64 + chunk);
#pragma unroll
      for (int fi = 0; fi < 4; ++fi)
#pragma unroll
        for (int fj = 0; fj < 4; ++fj)
          acc[fi][fj] = __builtin_amdgcn_mfma_f32_16x16x32_bf16(av[fi], bv[fj], acc[fi][fj], 0, 0, 0);
    }
    __syncthreads();
  }

  // epilogue: bias+relu -> bf16 into per-wave-private LDS tile, then coalesced stores
  ushort* eb = smem + w * 4096;   // 64x64 ushorts per wave
#pragma unroll
  for (int fj = 0; fj < 4; ++fj) {
    float bias = b1[c0 + wn * 64 + fj * 16 + l15];
#pragma unroll
    for (int fi = 0; fi < 4; ++fi) {
#pragma unroll
      for (int r = 0; r < 4; ++r) {
        float v = fmaxf(acc[fi][fj][r] + bias, 0.f);
        eb[(fi * 16 + quad * 4 + r) * 64 + fj * 16 + l15] = f2bf(v);
      }
    }
  }
  // wave-private region: no barrier needed (lgkmcnt ordering within wave)
#pragma unroll
  for (int i = 0; i < 16; ++i) {
    int row = i * 4 + (lane >> 4);
    uint2 v = *(const uint2*)(eb + row * 64 + l15 * 4);
    *(uint2*)(h1b + (size_t)(i0 + wm * 64 + row) * 256 + c0 + wn * 64 + l15 * 4) = v;
  }
}

// ---------------- MFMA GEMM2 + bias + log_softmax: out[N2,64] fp32
__global__ __launch_bounds__(256) void mgemm2_kernel(
    const ushort* __restrict__ aggr2, const ushort* __restrict__ h1b,
    const ushort* __restrict__ W2lb, const ushort* __restrict__ W2rb,
    const float* __restrict__ b2, float* __restrict__ out) {
  __shared__ ushort sA[64 * 64];
  __shared__ ushort sB[64 * 64];
  int t = threadIdx.x;
  int lane = t & 63;
  int w = t >> 6;
  int i0 = blockIdx.x * 64;

  int sr = t >> 3;
  int sc = (t & 7) ^ (sr & 7);
  int quad = lane >> 4;
  int l15 = lane & 15;
  int xorv = lane & 7;

  f32x4 acc[4];
#pragma unroll
  for (int j = 0; j < 4; ++j) acc[j] = (f32x4)(0.f);

  for (int kt = 0; kt < 8; ++kt) {
    const ushort* Asrc = (kt < 4) ? aggr2 : h1b;
    const ushort* Bsrc = (kt < 4) ? W2lb : W2rb;
    int koff = (kt & 3) * 64;
#pragma unroll
    for (int it = 0; it < 2; ++it) {
      int r = it * 32 + sr;
      gl_lds16(Asrc + (size_t)(i0 + r) * 256 + koff + sc * 8, sA + (it * 256 + t) * 8);
    }
#pragma unroll
    for (int it = 0; it < 2; ++it) {
      int r = it * 32 + sr;
      gl_lds16(Bsrc + (size_t)r * 256 + koff + sc * 8, sB + (it * 256 + t) * 8);
    }
    __syncthreads();
#pragma unroll
    for (int s = 0; s < 2; ++s) {
      int chunk = ((s * 4 + quad) ^ xorv) * 8;
      bf16x8 av = *(const bf16x8*)(sA + (w * 16 + l15) * 64 + chunk);
      bf16x8 bv[4];
#pragma unroll
      for (int fj = 0; fj < 4; ++fj)
        bv[fj] = *(const bf16x8*)(sB + (fj * 16 + l15) * 64 + chunk);
#pragma unroll
      for (int fj = 0; fj < 4; ++fj)
        acc[fj] = __builtin_amdgcn_mfma_f32_16x16x32_bf16(av, bv[fj], acc[fj], 0, 0, 0);
    }
    __syncthreads();
  }

  float b2c[4];
#pragma unroll
  for (int fj = 0; fj < 4; ++fj) b2c[fj] = b2[fj * 16 + l15];

#pragma unroll
  for (int r = 0; r < 4; ++r) {
    int row = i0 + w * 16 + quad * 4 + r;
    float v[4];
#pragma unroll
    for (int fj = 0; fj < 4; ++fj) v[fj] = acc[fj][r] + b2c[fj];
    float m = fmaxf(fmaxf(v[0], v[1]), fmaxf(v[2], v[3]));
    m = fmaxf(m, __shfl_xor(m, 1));
    m = fmaxf(m, __shfl_xor(m, 2));
    m = fmaxf(m, __shfl_xor(m, 4));
    m = fmaxf(m, __shfl_xor(m, 8));
    float ssum = __expf(v[0] - m) + __expf(v[1] - m) + __expf(v[2] - m) + __expf(v[3] - m);
    ssum += __shfl_xor(ssum, 1);
    ssum += __shfl_xor(ssum, 2);
    ssum += __shfl_xor(ssum, 4);
    ssum += __shfl_xor(ssum, 8);
    float lg = m + __logf(ssum);
#pragma unroll
    for (int fj = 0; fj < 4; ++fj)
      out[(size_t)row * 64 + fj * 16 + l15] = v[fj] - lg;
  }
}

// ---------------- launch ----------------

extern "C" void kernel_launch(void* const* d_in, const int* in_sizes, int n_in,
                              void* d_out, int out_size, void* d_ws, size_t ws_size,
                              hipStream_t stream) {
  const float* x   = (const float*)d_in[0];
  const int* src1  = (const int*)d_in[1];
  const int* dst1  = (const int*)d_in[2];
  const int* src2  = (const int*)d_in[3];
  const int* dst2  = (const int*)d_in[4];
  const float* W1l = (const float*)d_in[5];
  const float* W1r = (const float*)d_in[6];
  const float* b1  = (const float*)d_in[7];
  const float* W2l = (const float*)d_in[8];
  const float* W2r = (const float*)d_in[9];
  const float* b2  = (const float*)d_in[10];
  float* out = (float*)d_out;

  char* base = (char*)d_ws;
  ushort* xb   = (ushort*)base;                          // 67.1 MB
  ushort* h1b  = (ushort*)(base + 67108864);             // 33.6 MB
  ushort* ag1b = (ushort*)(base + 100663296);            // 16.8 MB
  uint2* pair1 = (uint2*)(base + 117440512);             // 16.8 MB
  uint2* pair2 = (uint2*)(base + 134217728);             // 16.8 MB
  int* cnt1  = (int*)(base + 150994944);                 // N1
  int* off1  = cnt1 + N1C;                               // N1
  int* cnt2  = off1 + N1C;                               // N2
  int* off2  = cnt2 + N2C;                               // N2
  int* btail = off2 + N2C;                               // 512
  int* bbase = btail + 512;                              // 512
  int* ssrc1 = bbase + 512;                              // E1
  int* ssrc2 = ssrc1 + E1C;                              // E2
  ushort* W1lb = (ushort*)(ssrc2 + E2C);                 // 32768
  ushort* W1rb = W1lb + 32768;
  ushort* W2lb = W1rb + 32768;
  ushort* W2rb = W2lb + 16384;
  ushort* ag2b = xb;   // alias: aggr2 written after mgemm1's last read of xb

  // weights -> bf16 + btail zero (one fused kernel)
  cvtw_kernel<<<dim3(32, 5), 256, 0, stream>>>(
      (const float4*)W1l, (const float4*)W1r, (const float4*)W2l, (const float4*)W2r,
      (ushort4*)W1lb, (ushort4*)W1rb, (ushort4*)W2lb, (ushort4*)W2rb, btail);

  // x -> bf16
  cvtbf16_kernel<<<4096, 256, 0, stream>>>((const float4*)x, (ushort4*)xb, N0C * 128 / 4);

  // CSR build, both layers
  binA_kernel<8><<<E1C / 4096, 256, 0, stream>>>(src1, dst1, btail, pair1);
  binA_kernel<6><<<E2C / 4096, 256, 0, stream>>>(src2, dst2, btail + 256, pair2);
  scanB_kernel<<<2, 256, 0, stream>>>(btail, bbase);
  binB_kernel<256><<<256, 256, 0, stream>>>(pair1, btail, bbase, off1, cnt1, ssrc1);
  binB_kernel<64><<<256, 256, 0, stream>>>(pair2, btail + 256, bbase + 256, off2, cnt2, ssrc2);

  // layer 1
  agg1_kernel<<<N1C / 4, 256, 0, stream>>>(xb, ssrc1, off1, cnt1, ag1b);
  mgemm1_kernel<<<dim3(N1C / 128, 2), 256, 0, stream>>>(ag1b, xb, W1lb, W1rb, b1, h1b);

  // layer 2
  agg2_kernel<<<N2C / 4, 256, 0, stream>>>(h1b, ssrc2, off2, cnt2, ag2b);
  mgemm2_kernel<<<N2C / 64, 256, 0, stream>>>(ag2b, h1b, W2lb, W2rb, b2, out);
}

// Round 7
// 171.522 us; speedup vs baseline: 17.9276x; 1.0731x over previous
//
#include <hip/hip_runtime.h>
#include <cstdint>
#include <cstddef>

#define N0C 262144
#define N1C 65536
#define N2C 16384
#define E1C 1048576
#define E2C 262144
// IN_C=128, HID_C=256, OUT_C=64

typedef __attribute__((ext_vector_type(8))) short bf16x8;
typedef __attribute__((ext_vector_type(4))) float f32x4;

__device__ __forceinline__ unsigned short f2bf(float f) {
  union { float f; unsigned u; } q; q.f = f;
  unsigned r = q.u + 0x7fffu + ((q.u >> 16) & 1u);
  return (unsigned short)(r >> 16);
}
__device__ __forceinline__ float blo(unsigned u) {
  union { unsigned u; float f; } q; q.u = u << 16; return q.f;
}
__device__ __forceinline__ float bhi(unsigned u) {
  union { unsigned u; float f; } q; q.u = u & 0xffff0000u; return q.f;
}
__device__ __forceinline__ void gl_lds16(const void* g, void* l) {
  __builtin_amdgcn_global_load_lds((const __attribute__((address_space(1))) void*)g,
                                   (__attribute__((address_space(3))) void*)l, 16, 0, 0);
}

// ---------------- fused weight cvt + btail zero ----------------
__global__ __launch_bounds__(256) void cvtw_kernel(
    const float4* __restrict__ W1l, const float4* __restrict__ W1r,
    const float4* __restrict__ W2l, const float4* __restrict__ W2r,
    ushort4* __restrict__ W1lb, ushort4* __restrict__ W1rb,
    ushort4* __restrict__ W2lb, ushort4* __restrict__ W2rb,
    int* __restrict__ btail) {
  int y = blockIdx.y;
  int i = blockIdx.x * 256 + threadIdx.x;
  if (y == 4) {
    if (i < 512) btail[i] = 0;
    return;
  }
  const float4* in; ushort4* outp; int n4;
  if (y == 0)      { in = W1l; outp = W1lb; n4 = 8192; }
  else if (y == 1) { in = W1r; outp = W1rb; n4 = 8192; }
  else if (y == 2) { in = W2l; outp = W2lb; n4 = 4096; }
  else             { in = W2r; outp = W2rb; n4 = 4096; }
  if (i < n4) {
    float4 v = in[i];
    ushort4 o;
    o.x = f2bf(v.x); o.y = f2bf(v.y); o.z = f2bf(v.z); o.w = f2bf(v.w);
    outp[i] = o;
  }
}

// ---------------- binned counting sort (CSR build), both layers fused ----------------
// binA: blocks 0..255 = layer1 edges (4096 each); blocks 256..319 = layer2 edges
__global__ __launch_bounds__(256) void binA_kernel(
    const int* __restrict__ src1, const int* __restrict__ dst1,
    const int* __restrict__ src2, const int* __restrict__ dst2,
    int* __restrict__ btail, uint2* __restrict__ pair1, uint2* __restrict__ pair2) {
  __shared__ int hist[256];
  __shared__ int lofs[256];
  __shared__ int gbase[256];
  __shared__ int sstg[4096];
  __shared__ int dstg[4096];
  int b = blockIdx.x;
  int t = threadIdx.x;
  const int* src; const int* dst; int shift; int* bt; uint2* pb; int e0;
  if (b < 256) { src = src1; dst = dst1; shift = 8; bt = btail;       pb = pair1; e0 = b * 4096; }
  else         { src = src2; dst = dst2; shift = 6; bt = btail + 256; pb = pair2; e0 = (b - 256) * 4096; }
  hist[t] = 0;
  __syncthreads();
  int s_[16], d_[16], rk[16];
#pragma unroll
  for (int k = 0; k < 16; ++k) {
    int e = e0 + k * 256 + t;
    s_[k] = src[e];
    d_[k] = dst[e];
    rk[k] = atomicAdd(&hist[d_[k] >> shift], 1);
  }
  __syncthreads();
  int v = hist[t];
  lofs[t] = v;
  __syncthreads();
  for (int ofs = 1; ofs < 256; ofs <<= 1) {
    int add = (t >= ofs) ? lofs[t - ofs] : 0;
    __syncthreads();
    lofs[t] += add;
    __syncthreads();
  }
  gbase[t] = atomicAdd(&bt[t], v);
  int excl = lofs[t] - v;
  lofs[t] = excl;
  __syncthreads();
#pragma unroll
  for (int k = 0; k < 16; ++k) {
    int p = lofs[d_[k] >> shift] + rk[k];
    sstg[p] = s_[k];
    dstg[p] = d_[k];
  }
  __syncthreads();
  for (int i = t; i < 4096; i += 256) {
    int d = dstg[i];
    int bk = d >> shift;
    int idx = gbase[bk] + (i - lofs[bk]);
    if (idx < 8192)
      pb[(size_t)bk * 8192 + idx] = make_uint2((unsigned)sstg[i], (unsigned)d);
  }
}

// binB: one block per BUCKET. Layer1 = 256 buckets (blocks 0..255),
// layer2 = 256 buckets (blocks 256..511). Computes its own base by reducing
// btail, local hist+scan -> cnt/off, counting-sorts in LDS, streams ssrc.
__global__ __launch_bounds__(256) void binB_kernel(
    const uint2* __restrict__ pair1, const uint2* __restrict__ pair2,
    const int* __restrict__ btail,
    int* __restrict__ off1, int* __restrict__ cnt1, int* __restrict__ ssrc1,
    int* __restrict__ off2, int* __restrict__ cnt2, int* __restrict__ ssrc2) {
  __shared__ int lcnt[256];
  __shared__ int loff[256];
  __shared__ int lcnt2[256];
  __shared__ int stage[8192];
  int b = blockIdx.x;
  int t = threadIdx.x;
  const uint2* pb; const int* bt; int dpb; int* off; int* cnt; int* ssrc; int bl;
  if (b < 256) { bl = b;       pb = pair1 + (size_t)bl * 8192; bt = btail;       dpb = 256; off = off1; cnt = cnt1; ssrc = ssrc1; }
  else         { bl = b - 256; pb = pair2 + (size_t)bl * 8192; bt = btail + 256; dpb = 64;  off = off2; cnt = cnt2; ssrc = ssrc2; }
  // base = sum(bt[0..bl)) via LDS reduce
  lcnt[t] = (t < bl) ? bt[t] : 0;
  __syncthreads();
  for (int ofs = 128; ofs > 0; ofs >>= 1) {
    if (t < ofs) lcnt[t] += lcnt[t + ofs];
    __syncthreads();
  }
  int base = lcnt[0];
  __syncthreads();
  lcnt[t] = 0;
  lcnt2[t] = 0;
  __syncthreads();
  int n = bt[bl];
  if (n > 8192) n = 8192;
  for (int i = t; i < n; i += 256) {
    uint2 p = pb[i];
    atomicAdd(&lcnt[p.y & (dpb - 1)], 1);
  }
  __syncthreads();
  int v = lcnt[t];
  loff[t] = v;
  __syncthreads();
  for (int ofs = 1; ofs < 256; ofs <<= 1) {
    int add = (t >= ofs) ? loff[t - ofs] : 0;
    __syncthreads();
    loff[t] += add;
    __syncthreads();
  }
  int excl = loff[t] - v;
  loff[t] = excl;
  if (t < dpb) {
    cnt[bl * dpb + t] = v;
    off[bl * dpb + t] = base + excl;
  }
  __syncthreads();
  for (int i = t; i < n; i += 256) {
    uint2 p = pb[i];
    int dl = p.y & (dpb - 1);
    int r = atomicAdd(&lcnt2[dl], 1);
    stage[loff[dl] + r] = (int)p.x;
  }
  __syncthreads();
  for (int i = t; i < n; i += 256) ssrc[base + i] = stage[i];
}

// ---------------- layer-1 aggregation: fp32 gather, fused dst-row bf16 cvt ----------------
__global__ __launch_bounds__(256) void agg1_kernel(const float* __restrict__ x,
                                                   const int* __restrict__ ssrc,
                                                   const int* __restrict__ off,
                                                   const int* __restrict__ cnt,
                                                   ushort* __restrict__ aggr,
                                                   ushort* __restrict__ xbd) {
  int wid = (blockIdx.x * 256 + threadIdx.x) >> 6;
  int lane = threadIdx.x & 63;
  // fused cvt of x_dst row wid (exactly the rows mgemm1 needs)
  {
    float2 v = ((const float2*)(x + (size_t)wid * 128))[lane];
    unsigned o = (unsigned)f2bf(v.x) | ((unsigned)f2bf(v.y) << 16);
    *(unsigned*)(xbd + (size_t)wid * 128 + lane * 2) = o;
  }
  int grp = lane >> 4;
  int cl = lane & 15;
  int start = __builtin_amdgcn_readfirstlane(off[wid]);
  int n = __builtin_amdgcn_readfirstlane(cnt[wid]);
  float a0 = 0.f, a1 = 0.f, a2 = 0.f, a3 = 0.f, a4 = 0.f, a5 = 0.f, a6 = 0.f, a7 = 0.f;
  int j = 0;
  for (; j + 4 <= n; j += 4) {
    int s = ssrc[start + j + grp];
    const float4* row = (const float4*)(x + (size_t)s * 128);
    float4 va = row[cl * 2];
    float4 vb = row[cl * 2 + 1];
    a0 += va.x; a1 += va.y; a2 += va.z; a3 += va.w;
    a4 += vb.x; a5 += vb.y; a6 += vb.z; a7 += vb.w;
  }
  if (grp < n - j) {
    int s = ssrc[start + j + grp];
    const float4* row = (const float4*)(x + (size_t)s * 128);
    float4 va = row[cl * 2];
    float4 vb = row[cl * 2 + 1];
    a0 += va.x; a1 += va.y; a2 += va.z; a3 += va.w;
    a4 += vb.x; a5 += vb.y; a6 += vb.z; a7 += vb.w;
  }
#define RED1(v) v += __shfl_xor(v, 16); v += __shfl_xor(v, 32);
  RED1(a0) RED1(a1) RED1(a2) RED1(a3) RED1(a4) RED1(a5) RED1(a6) RED1(a7)
#undef RED1
  if (lane < 16) {
    float inv = (n > 0) ? 1.0f / (float)n : 0.f;
    uint4 o;
    o.x = (unsigned)f2bf(a0 * inv) | ((unsigned)f2bf(a1 * inv) << 16);
    o.y = (unsigned)f2bf(a2 * inv) | ((unsigned)f2bf(a3 * inv) << 16);
    o.z = (unsigned)f2bf(a4 * inv) | ((unsigned)f2bf(a5 * inv) << 16);
    o.w = (unsigned)f2bf(a6 * inv) | ((unsigned)f2bf(a7 * inv) << 16);
    *(uint4*)(aggr + (size_t)wid * 128 + cl * 8) = o;
  }
}

// ---------------- layer-2 aggregation: bf16 gather from h1b ----------------
__global__ __launch_bounds__(256) void agg2_kernel(const ushort* __restrict__ h1b,
                                                   const int* __restrict__ ssrc,
                                                   const int* __restrict__ off,
                                                   const int* __restrict__ cnt,
                                                   ushort* __restrict__ aggr) {
  int wid = (blockIdx.x * 256 + threadIdx.x) >> 6;
  int lane = threadIdx.x & 63;
  int grp = lane >> 5;
  int cl = lane & 31;
  int start = __builtin_amdgcn_readfirstlane(off[wid]);
  int n = __builtin_amdgcn_readfirstlane(cnt[wid]);
  float a0 = 0.f, a1 = 0.f, a2 = 0.f, a3 = 0.f, a4 = 0.f, a5 = 0.f, a6 = 0.f, a7 = 0.f;
  int j = 0;
  for (; j + 4 <= n; j += 4) {
    int sa = ssrc[start + j + grp];
    int sb = ssrc[start + j + 2 + grp];
    uint4 va = *(const uint4*)(h1b + (size_t)sa * 256 + cl * 8);
    uint4 vb = *(const uint4*)(h1b + (size_t)sb * 256 + cl * 8);
    a0 += blo(va.x) + blo(vb.x); a1 += bhi(va.x) + bhi(vb.x);
    a2 += blo(va.y) + blo(vb.y); a3 += bhi(va.y) + bhi(vb.y);
    a4 += blo(va.z) + blo(vb.z); a5 += bhi(va.z) + bhi(vb.z);
    a6 += blo(va.w) + blo(vb.w); a7 += bhi(va.w) + bhi(vb.w);
  }
  if (j + 2 <= n) {
    int s = ssrc[start + j + grp];
    uint4 v = *(const uint4*)(h1b + (size_t)s * 256 + cl * 8);
    a0 += blo(v.x); a1 += bhi(v.x); a2 += blo(v.y); a3 += bhi(v.y);
    a4 += blo(v.z); a5 += bhi(v.z); a6 += blo(v.w); a7 += bhi(v.w);
    j += 2;
  }
  if (grp < n - j) {
    int s = ssrc[start + j + grp];
    uint4 v = *(const uint4*)(h1b + (size_t)s * 256 + cl * 8);
    a0 += blo(v.x); a1 += bhi(v.x); a2 += blo(v.y); a3 += bhi(v.y);
    a4 += blo(v.z); a5 += bhi(v.z); a6 += blo(v.w); a7 += bhi(v.w);
  }
#define RED2(v) v += __shfl_xor(v, 32);
  RED2(a0) RED2(a1) RED2(a2) RED2(a3) RED2(a4) RED2(a5) RED2(a6) RED2(a7)
#undef RED2
  if (lane < 32) {
    float inv = (n > 0) ? 1.0f / (float)n : 0.f;
    uint4 o;
    o.x = (unsigned)f2bf(a0 * inv) | ((unsigned)f2bf(a1 * inv) << 16);
    o.y = (unsigned)f2bf(a2 * inv) | ((unsigned)f2bf(a3 * inv) << 16);
    o.z = (unsigned)f2bf(a4 * inv) | ((unsigned)f2bf(a5 * inv) << 16);
    o.w = (unsigned)f2bf(a6 * inv) | ((unsigned)f2bf(a7 * inv) << 16);
    *(uint4*)(aggr + (size_t)wid * 256 + cl * 8) = o;
  }
}

// ---------------- MFMA GEMM1: [N1,256] = relu([aggr1|xbd] @ [W1l|W1r]^T + b1), bf16 out
// 512 threads, 128x256 tile (full N) -> A read once. 8 waves (2x4), 64x64 each.
__global__ __launch_bounds__(512) void mgemm1_kernel(
    const ushort* __restrict__ aggr1, const ushort* __restrict__ xbd,
    const ushort* __restrict__ W1lb, const ushort* __restrict__ W1rb,
    const float* __restrict__ b1, ushort* __restrict__ h1b) {
  __shared__ ushort smem[24576];   // sA 8192 + sB 16384 ushorts = 48KB
  ushort* sA = smem;
  ushort* sB = smem + 8192;
  int t = threadIdx.x;
  int lane = t & 63;
  int w = t >> 6;
  int wm = w >> 2, wn = w & 3;
  int i0 = blockIdx.x * 128;

  int sr = t >> 3;                 // 0..63
  int sc = (t & 7) ^ (sr & 7);     // swizzled source chunk
  int quad = lane >> 4;
  int l15 = lane & 15;
  int xorv = lane & 7;

  f32x4 acc[4][4];
#pragma unroll
  for (int i = 0; i < 4; ++i)
#pragma unroll
    for (int j = 0; j < 4; ++j) acc[i][j] = (f32x4)(0.f);

  for (int kt = 0; kt < 4; ++kt) {
    const ushort* Asrc = (kt < 2) ? aggr1 : xbd;
    const ushort* Bsrc = (kt < 2) ? W1lb : W1rb;
    int koff = (kt & 1) * 64;
#pragma unroll
    for (int it = 0; it < 2; ++it) {
      int r = it * 64 + sr;
      gl_lds16(Asrc + (size_t)(i0 + r) * 128 + koff + sc * 8, sA + (it * 512 + t) * 8);
    }
#pragma unroll
    for (int it = 0; it < 4; ++it) {
      int r = it * 64 + sr;
      gl_lds16(Bsrc + (size_t)r * 128 + koff + sc * 8, sB + (it * 512 + t) * 8);
    }
    __syncthreads();
#pragma unroll
    for (int s = 0; s < 2; ++s) {
      int chunk = ((s * 4 + quad) ^ xorv) * 8;
      bf16x8 av[4], bv[4];
#pragma unroll
      for (int fi = 0; fi < 4; ++fi)
        av[fi] = *(const bf16x8*)(sA + (wm * 64 + fi * 16 + l15) * 64 + chunk);
#pragma unroll
      for (int fj = 0; fj < 4; ++fj)
        bv[fj] = *(const bf16x8*)(sB + (wn * 64 + fj * 16 + l15) * 64 + chunk);
#pragma unroll
      for (int fi = 0; fi < 4; ++fi)
#pragma unroll
        for (int fj = 0; fj < 4; ++fj)
          acc[fi][fj] = __builtin_amdgcn_mfma_f32_16x16x32_bf16(av[fi], bv[fj], acc[fi][fj], 0, 0, 0);
    }
    __syncthreads();
  }

  // two-phase epilogue: 4 waves at a time stage 64x64 bf16 in LDS, store uint2
  for (int ph = 0; ph < 2; ++ph) {
    if (wm == ph) {
      ushort* eb = smem + (w & 3) * 4096;
#pragma unroll
      for (int fj = 0; fj < 4; ++fj) {
        float bias = b1[wn * 64 + fj * 16 + l15];
#pragma unroll
        for (int fi = 0; fi < 4; ++fi)
#pragma unroll
          for (int r = 0; r < 4; ++r) {
            float v = fmaxf(acc[fi][fj][r] + bias, 0.f);
            eb[(fi * 16 + quad * 4 + r) * 64 + fj * 16 + l15] = f2bf(v);
          }
      }
#pragma unroll
      for (int i = 0; i < 16; ++i) {
        int row = i * 4 + (lane >> 4);
        uint2 v = *(const uint2*)(eb + row * 64 + l15 * 4);
        *(uint2*)(h1b + (size_t)(i0 + wm * 64 + row) * 256 + wn * 64 + l15 * 4) = v;
      }
    }
    __syncthreads();
  }
}

// ---------------- MFMA GEMM2 + bias + log_softmax: out[N2,64] fp32 ----------------
__global__ __launch_bounds__(256) void mgemm2_kernel(
    const ushort* __restrict__ aggr2, const ushort* __restrict__ h1b,
    const ushort* __restrict__ W2lb, const ushort* __restrict__ W2rb,
    const float* __restrict__ b2, float* __restrict__ out) {
  __shared__ ushort sA[64 * 64];
  __shared__ ushort sB[64 * 64];
  int t = threadIdx.x;
  int lane = t & 63;
  int w = t >> 6;
  int i0 = blockIdx.x * 64;

  int sr = t >> 3;
  int sc = (t & 7) ^ (sr & 7);
  int quad = lane >> 4;
  int l15 = lane & 15;
  int xorv = lane & 7;

  f32x4 acc[4];
#pragma unroll
  for (int j = 0; j < 4; ++j) acc[j] = (f32x4)(0.f);

  for (int kt = 0; kt < 8; ++kt) {
    const ushort* Asrc = (kt < 4) ? aggr2 : h1b;
    const ushort* Bsrc = (kt < 4) ? W2lb : W2rb;
    int koff = (kt & 3) * 64;
#pragma unroll
    for (int it = 0; it < 2; ++it) {
      int r = it * 32 + sr;
      gl_lds16(Asrc + (size_t)(i0 + r) * 256 + koff + sc * 8, sA + (it * 256 + t) * 8);
    }
#pragma unroll
    for (int it = 0; it < 2; ++it) {
      int r = it * 32 + sr;
      gl_lds16(Bsrc + (size_t)r * 256 + koff + sc * 8, sB + (it * 256 + t) * 8);
    }
    __syncthreads();
#pragma unroll
    for (int s = 0; s < 2; ++s) {
      int chunk = ((s * 4 + quad) ^ xorv) * 8;
      bf16x8 av = *(const bf16x8*)(sA + (w * 16 + l15) * 64 + chunk);
      bf16x8 bv[4];
#pragma unroll
      for (int fj = 0; fj < 4; ++fj)
        bv[fj] = *(const bf16x8*)(sB + (fj * 16 + l15) * 64 + chunk);
#pragma unroll
      for (int fj = 0; fj < 4; ++fj)
        acc[fj] = __builtin_amdgcn_mfma_f32_16x16x32_bf16(av, bv[fj], acc[fj], 0, 0, 0);
    }
    __syncthreads();
  }

  float b2c[4];
#pragma unroll
  for (int fj = 0; fj < 4; ++fj) b2c[fj] = b2[fj * 16 + l15];

#pragma unroll
  for (int r = 0; r < 4; ++r) {
    int row = i0 + w * 16 + quad * 4 + r;
    float v[4];
#pragma unroll
    for (int fj = 0; fj < 4; ++fj) v[fj] = acc[fj][r] + b2c[fj];
    float m = fmaxf(fmaxf(v[0], v[1]), fmaxf(v[2], v[3]));
    m = fmaxf(m, __shfl_xor(m, 1));
    m = fmaxf(m, __shfl_xor(m, 2));
    m = fmaxf(m, __shfl_xor(m, 4));
    m = fmaxf(m, __shfl_xor(m, 8));
    float ssum = __expf(v[0] - m) + __expf(v[1] - m) + __expf(v[2] - m) + __expf(v[3] - m);
    ssum += __shfl_xor(ssum, 1);
    ssum += __shfl_xor(ssum, 2);
    ssum += __shfl_xor(ssum, 4);
    ssum += __shfl_xor(ssum, 8);
    float lg = m + __logf(ssum);
#pragma unroll
    for (int fj = 0; fj < 4; ++fj)
      out[(size_t)row * 64 + fj * 16 + l15] = v[fj] - lg;
  }
}

// ---------------- launch ----------------

extern "C" void kernel_launch(void* const* d_in, const int* in_sizes, int n_in,
                              void* d_out, int out_size, void* d_ws, size_t ws_size,
                              hipStream_t stream) {
  const float* x   = (const float*)d_in[0];
  const int* src1  = (const int*)d_in[1];
  const int* dst1  = (const int*)d_in[2];
  const int* src2  = (const int*)d_in[3];
  const int* dst2  = (const int*)d_in[4];
  const float* W1l = (const float*)d_in[5];
  const float* W1r = (const float*)d_in[6];
  const float* b1  = (const float*)d_in[7];
  const float* W2l = (const float*)d_in[8];
  const float* W2r = (const float*)d_in[9];
  const float* b2  = (const float*)d_in[10];
  float* out = (float*)d_out;

  char* base = (char*)d_ws;
  ushort* ag1b = (ushort*)base;                          // N1*128 = 16.8 MB
  ushort* xbd  = (ushort*)(base + 16777216);             // N1*128 = 16.8 MB
  ushort* h1b  = (ushort*)(base + 33554432);             // N1*256 = 33.6 MB
  ushort* ag2b = (ushort*)(base + 67108864);             // N2*256 = 8.4 MB
  uint2* pair1 = (uint2*)(base + 75497472);              // 16.8 MB
  uint2* pair2 = (uint2*)(base + 92274688);              // 16.8 MB
  int* cnt1  = (int*)(base + 109051904);                 // N1
  int* off1  = cnt1 + N1C;                               // N1
  int* cnt2  = off1 + N1C;                               // N2
  int* off2  = cnt2 + N2C;                               // N2
  int* btail = off2 + N2C;                               // 512
  int* ssrc1 = btail + 512;                              // E1
  int* ssrc2 = ssrc1 + E1C;                              // E2
  ushort* W1lb = (ushort*)(ssrc2 + E2C);                 // 32768
  ushort* W1rb = W1lb + 32768;
  ushort* W2lb = W1rb + 32768;
  ushort* W2rb = W2lb + 16384;

  // weights -> bf16 + btail zero
  cvtw_kernel<<<dim3(32, 5), 256, 0, stream>>>(
      (const float4*)W1l, (const float4*)W1r, (const float4*)W2l, (const float4*)W2r,
      (ushort4*)W1lb, (ushort4*)W1rb, (ushort4*)W2lb, (ushort4*)W2rb, btail);

  // CSR build, both layers, 2 launches
  binA_kernel<<<320, 256, 0, stream>>>(src1, dst1, src2, dst2, btail, pair1, pair2);
  binB_kernel<<<512, 256, 0, stream>>>(pair1, pair2, btail,
                                       off1, cnt1, ssrc1, off2, cnt2, ssrc2);

  // layer 1: fp32 gather + fused dst-row cvt, then MFMA GEMM
  agg1_kernel<<<N1C / 4, 256, 0, stream>>>(x, ssrc1, off1, cnt1, ag1b, xbd);
  mgemm1_kernel<<<N1C / 128, 512, 0, stream>>>(ag1b, xbd, W1lb, W1rb, b1, h1b);

  // layer 2
  agg2_kernel<<<N2C / 4, 256, 0, stream>>>(h1b, ssrc2, off2, cnt2, ag2b);
  mgemm2_kernel<<<N2C / 64, 256, 0, stream>>>(ag2b, h1b, W2lb, W2rb, b2, out);
}

// Round 8
// 167.133 us; speedup vs baseline: 18.3983x; 1.0263x over previous
//
#include <hip/hip_runtime.h>
#include <cstdint>
#include <cstddef>

#define N0C 262144
#define N1C 65536
#define N2C 16384
#define E1C 1048576
#define E2C 262144
// IN_C=128, HID_C=256, OUT_C=64

typedef __attribute__((ext_vector_type(8))) short bf16x8;
typedef __attribute__((ext_vector_type(4))) float f32x4;

__device__ __forceinline__ unsigned short f2bf(float f) {
  union { float f; unsigned u; } q; q.f = f;
  unsigned r = q.u + 0x7fffu + ((q.u >> 16) & 1u);
  return (unsigned short)(r >> 16);
}
__device__ __forceinline__ float blo(unsigned u) {
  union { unsigned u; float f; } q; q.u = u << 16; return q.f;
}
__device__ __forceinline__ float bhi(unsigned u) {
  union { unsigned u; float f; } q; q.u = u & 0xffff0000u; return q.f;
}
__device__ __forceinline__ void gl_lds16(const void* g, void* l) {
  __builtin_amdgcn_global_load_lds((const __attribute__((address_space(1))) void*)g,
                                   (__attribute__((address_space(3))) void*)l, 16, 0, 0);
}

// ---------------- fp32 -> bf16: x (full N0) ----------------
__global__ void cvtx_kernel(const float4* __restrict__ in, ushort4* __restrict__ out, int n4) {
  int i = blockIdx.x * blockDim.x + threadIdx.x;
  int stride = gridDim.x * blockDim.x;
  for (; i < n4; i += stride) {
    float4 v = in[i];
    ushort4 o;
    o.x = f2bf(v.x); o.y = f2bf(v.y); o.z = f2bf(v.z); o.w = f2bf(v.w);
    out[i] = o;
  }
}

// ---------------- fused weight cvt + btail zero ----------------
__global__ __launch_bounds__(256) void cvtw_kernel(
    const float4* __restrict__ W1l, const float4* __restrict__ W1r,
    const float4* __restrict__ W2l, const float4* __restrict__ W2r,
    ushort4* __restrict__ W1lb, ushort4* __restrict__ W1rb,
    ushort4* __restrict__ W2lb, ushort4* __restrict__ W2rb,
    int* __restrict__ btail) {
  int y = blockIdx.y;
  int i = blockIdx.x * 256 + threadIdx.x;
  if (y == 4) {
    if (i < 512) btail[i] = 0;
    return;
  }
  const float4* in; ushort4* outp; int n4;
  if (y == 0)      { in = W1l; outp = W1lb; n4 = 8192; }
  else if (y == 1) { in = W1r; outp = W1rb; n4 = 8192; }
  else if (y == 2) { in = W2l; outp = W2lb; n4 = 4096; }
  else             { in = W2r; outp = W2rb; n4 = 4096; }
  if (i < n4) {
    float4 v = in[i];
    ushort4 o;
    o.x = f2bf(v.x); o.y = f2bf(v.y); o.z = f2bf(v.z); o.w = f2bf(v.w);
    outp[i] = o;
  }
}

// ---------------- binned counting sort (CSR build), both layers fused ----------------
// binA: blocks 0..255 = layer1 edges (4096 each); blocks 256..319 = layer2 edges
__global__ __launch_bounds__(256) void binA_kernel(
    const int* __restrict__ src1, const int* __restrict__ dst1,
    const int* __restrict__ src2, const int* __restrict__ dst2,
    int* __restrict__ btail, uint2* __restrict__ pair1, uint2* __restrict__ pair2) {
  __shared__ int hist[256];
  __shared__ int lofs[256];
  __shared__ int gbase[256];
  __shared__ int sstg[4096];
  __shared__ int dstg[4096];
  int b = blockIdx.x;
  int t = threadIdx.x;
  const int* src; const int* dst; int shift; int* bt; uint2* pb; int e0;
  if (b < 256) { src = src1; dst = dst1; shift = 8; bt = btail;       pb = pair1; e0 = b * 4096; }
  else         { src = src2; dst = dst2; shift = 6; bt = btail + 256; pb = pair2; e0 = (b - 256) * 4096; }
  hist[t] = 0;
  __syncthreads();
  int s_[16], d_[16], rk[16];
#pragma unroll
  for (int k = 0; k < 16; ++k) {
    int e = e0 + k * 256 + t;
    s_[k] = src[e];
    d_[k] = dst[e];
    rk[k] = atomicAdd(&hist[d_[k] >> shift], 1);
  }
  __syncthreads();
  int v = hist[t];
  lofs[t] = v;
  __syncthreads();
  for (int ofs = 1; ofs < 256; ofs <<= 1) {
    int add = (t >= ofs) ? lofs[t - ofs] : 0;
    __syncthreads();
    lofs[t] += add;
    __syncthreads();
  }
  gbase[t] = atomicAdd(&bt[t], v);
  int excl = lofs[t] - v;
  lofs[t] = excl;
  __syncthreads();
#pragma unroll
  for (int k = 0; k < 16; ++k) {
    int p = lofs[d_[k] >> shift] + rk[k];
    sstg[p] = s_[k];
    dstg[p] = d_[k];
  }
  __syncthreads();
  for (int i = t; i < 4096; i += 256) {
    int d = dstg[i];
    int bk = d >> shift;
    int idx = gbase[bk] + (i - lofs[bk]);
    if (idx < 8192)
      pb[(size_t)bk * 8192 + idx] = make_uint2((unsigned)sstg[i], (unsigned)d);
  }
}

// binB: one block per BUCKET (layer1: 0..255, layer2: 256..511).
__global__ __launch_bounds__(256) void binB_kernel(
    const uint2* __restrict__ pair1, const uint2* __restrict__ pair2,
    const int* __restrict__ btail,
    int* __restrict__ off1, int* __restrict__ cnt1, int* __restrict__ ssrc1,
    int* __restrict__ off2, int* __restrict__ cnt2, int* __restrict__ ssrc2) {
  __shared__ int lcnt[256];
  __shared__ int loff[256];
  __shared__ int lcnt2[256];
  __shared__ int stage[8192];
  int b = blockIdx.x;
  int t = threadIdx.x;
  const uint2* pb; const int* bt; int dpb; int* off; int* cnt; int* ssrc; int bl;
  if (b < 256) { bl = b;       pb = pair1 + (size_t)bl * 8192; bt = btail;       dpb = 256; off = off1; cnt = cnt1; ssrc = ssrc1; }
  else         { bl = b - 256; pb = pair2 + (size_t)bl * 8192; bt = btail + 256; dpb = 64;  off = off2; cnt = cnt2; ssrc = ssrc2; }
  // base = sum(bt[0..bl)) via LDS reduce
  lcnt[t] = (t < bl) ? bt[t] : 0;
  __syncthreads();
  for (int ofs = 128; ofs > 0; ofs >>= 1) {
    if (t < ofs) lcnt[t] += lcnt[t + ofs];
    __syncthreads();
  }
  int base = lcnt[0];
  __syncthreads();
  lcnt[t] = 0;
  lcnt2[t] = 0;
  __syncthreads();
  int n = bt[bl];
  if (n > 8192) n = 8192;
  for (int i = t; i < n; i += 256) {
    uint2 p = pb[i];
    atomicAdd(&lcnt[p.y & (dpb - 1)], 1);
  }
  __syncthreads();
  int v = lcnt[t];
  loff[t] = v;
  __syncthreads();
  for (int ofs = 1; ofs < 256; ofs <<= 1) {
    int add = (t >= ofs) ? loff[t - ofs] : 0;
    __syncthreads();
    loff[t] += add;
    __syncthreads();
  }
  int excl = loff[t] - v;
  loff[t] = excl;
  if (t < dpb) {
    cnt[bl * dpb + t] = v;
    off[bl * dpb + t] = base + excl;
  }
  __syncthreads();
  for (int i = t; i < n; i += 256) {
    uint2 p = pb[i];
    int dl = p.y & (dpb - 1);
    int r = atomicAdd(&lcnt2[dl], 1);
    stage[loff[dl] + r] = (int)p.x;
  }
  __syncthreads();
  for (int i = t; i < n; i += 256) ssrc[base + i] = stage[i];
}

// ---------------- layer-1 aggregation: bf16 gather (L3-resident xb) ----------------
// wave = 1 dst; 16 lanes x uint4 cover the 256B bf16 row; 4 edges in flight
__global__ __launch_bounds__(256) void agg1_kernel(const ushort* __restrict__ xb,
                                                   const int* __restrict__ ssrc,
                                                   const int* __restrict__ off,
                                                   const int* __restrict__ cnt,
                                                   ushort* __restrict__ aggr) {
  int wid = (blockIdx.x * 256 + threadIdx.x) >> 6;
  int lane = threadIdx.x & 63;
  int grp = lane >> 4;
  int cl = lane & 15;
  int start = __builtin_amdgcn_readfirstlane(off[wid]);
  int n = __builtin_amdgcn_readfirstlane(cnt[wid]);
  float a0 = 0.f, a1 = 0.f, a2 = 0.f, a3 = 0.f, a4 = 0.f, a5 = 0.f, a6 = 0.f, a7 = 0.f;
  int j = 0;
  for (; j + 4 <= n; j += 4) {
    int s = ssrc[start + j + grp];
    uint4 v = *(const uint4*)(xb + (size_t)s * 128 + cl * 8);
    a0 += blo(v.x); a1 += bhi(v.x); a2 += blo(v.y); a3 += bhi(v.y);
    a4 += blo(v.z); a5 += bhi(v.z); a6 += blo(v.w); a7 += bhi(v.w);
  }
  if (grp < n - j) {
    int s = ssrc[start + j + grp];
    uint4 v = *(const uint4*)(xb + (size_t)s * 128 + cl * 8);
    a0 += blo(v.x); a1 += bhi(v.x); a2 += blo(v.y); a3 += bhi(v.y);
    a4 += blo(v.z); a5 += bhi(v.z); a6 += blo(v.w); a7 += bhi(v.w);
  }
#define RED1(v) v += __shfl_xor(v, 16); v += __shfl_xor(v, 32);
  RED1(a0) RED1(a1) RED1(a2) RED1(a3) RED1(a4) RED1(a5) RED1(a6) RED1(a7)
#undef RED1
  if (lane < 16) {
    float inv = (n > 0) ? 1.0f / (float)n : 0.f;
    uint4 o;
    o.x = (unsigned)f2bf(a0 * inv) | ((unsigned)f2bf(a1 * inv) << 16);
    o.y = (unsigned)f2bf(a2 * inv) | ((unsigned)f2bf(a3 * inv) << 16);
    o.z = (unsigned)f2bf(a4 * inv) | ((unsigned)f2bf(a5 * inv) << 16);
    o.w = (unsigned)f2bf(a6 * inv) | ((unsigned)f2bf(a7 * inv) << 16);
    *(uint4*)(aggr + (size_t)wid * 128 + cl * 8) = o;
  }
}

// ---------------- layer-2 aggregation: bf16 gather from h1b ----------------
__global__ __launch_bounds__(256) void agg2_kernel(const ushort* __restrict__ h1b,
                                                   const int* __restrict__ ssrc,
                                                   const int* __restrict__ off,
                                                   const int* __restrict__ cnt,
                                                   ushort* __restrict__ aggr) {
  int wid = (blockIdx.x * 256 + threadIdx.x) >> 6;
  int lane = threadIdx.x & 63;
  int grp = lane >> 5;
  int cl = lane & 31;
  int start = __builtin_amdgcn_readfirstlane(off[wid]);
  int n = __builtin_amdgcn_readfirstlane(cnt[wid]);
  float a0 = 0.f, a1 = 0.f, a2 = 0.f, a3 = 0.f, a4 = 0.f, a5 = 0.f, a6 = 0.f, a7 = 0.f;
  int j = 0;
  for (; j + 4 <= n; j += 4) {
    int sa = ssrc[start + j + grp];
    int sb = ssrc[start + j + 2 + grp];
    uint4 va = *(const uint4*)(h1b + (size_t)sa * 256 + cl * 8);
    uint4 vb = *(const uint4*)(h1b + (size_t)sb * 256 + cl * 8);
    a0 += blo(va.x) + blo(vb.x); a1 += bhi(va.x) + bhi(vb.x);
    a2 += blo(va.y) + blo(vb.y); a3 += bhi(va.y) + bhi(vb.y);
    a4 += blo(va.z) + blo(vb.z); a5 += bhi(va.z) + bhi(vb.z);
    a6 += blo(va.w) + blo(vb.w); a7 += bhi(va.w) + bhi(vb.w);
  }
  if (j + 2 <= n) {
    int s = ssrc[start + j + grp];
    uint4 v = *(const uint4*)(h1b + (size_t)s * 256 + cl * 8);
    a0 += blo(v.x); a1 += bhi(v.x); a2 += blo(v.y); a3 += bhi(v.y);
    a4 += blo(v.z); a5 += bhi(v.z); a6 += blo(v.w); a7 += bhi(v.w);
    j += 2;
  }
  if (grp < n - j) {
    int s = ssrc[start + j + grp];
    uint4 v = *(const uint4*)(h1b + (size_t)s * 256 + cl * 8);
    a0 += blo(v.x); a1 += bhi(v.x); a2 += blo(v.y); a3 += bhi(v.y);
    a4 += blo(v.z); a5 += bhi(v.z); a6 += blo(v.w); a7 += bhi(v.w);
  }
#define RED2(v) v += __shfl_xor(v, 32);
  RED2(a0) RED2(a1) RED2(a2) RED2(a3) RED2(a4) RED2(a5) RED2(a6) RED2(a7)
#undef RED2
  if (lane < 32) {
    float inv = (n > 0) ? 1.0f / (float)n : 0.f;
    uint4 o;
    o.x = (unsigned)f2bf(a0 * inv) | ((unsigned)f2bf(a1 * inv) << 16);
    o.y = (unsigned)f2bf(a2 * inv) | ((unsigned)f2bf(a3 * inv) << 16);
    o.z = (unsigned)f2bf(a4 * inv) | ((unsigned)f2bf(a5 * inv) << 16);
    o.w = (unsigned)f2bf(a6 * inv) | ((unsigned)f2bf(a7 * inv) << 16);
    *(uint4*)(aggr + (size_t)wid * 256 + cl * 8) = o;
  }
}

// ---------------- MFMA GEMM1: [N1,256] = relu([aggr1|xb] @ [W1l|W1r]^T + b1), bf16 out
// 512 threads, 128x256 tile (full N) -> A read once. 8 waves (2x4), 64x64 each.
__global__ __launch_bounds__(512) void mgemm1_kernel(
    const ushort* __restrict__ aggr1, const ushort* __restrict__ xb,
    const ushort* __restrict__ W1lb, const ushort* __restrict__ W1rb,
    const float* __restrict__ b1, ushort* __restrict__ h1b) {
  __shared__ ushort smem[24576];   // sA 8192 + sB 16384 ushorts = 48KB
  ushort* sA = smem;
  ushort* sB = smem + 8192;
  int t = threadIdx.x;
  int lane = t & 63;
  int w = t >> 6;
  int wm = w >> 2, wn = w & 3;
  int i0 = blockIdx.x * 128;

  int sr = t >> 3;                 // 0..63
  int sc = (t & 7) ^ (sr & 7);     // swizzled source chunk
  int quad = lane >> 4;
  int l15 = lane & 15;
  int xorv = lane & 7;

  f32x4 acc[4][4];
#pragma unroll
  for (int i = 0; i < 4; ++i)
#pragma unroll
    for (int j = 0; j < 4; ++j) acc[i][j] = (f32x4)(0.f);

  for (int kt = 0; kt < 4; ++kt) {
    const ushort* Asrc = (kt < 2) ? aggr1 : xb;
    const ushort* Bsrc = (kt < 2) ? W1lb : W1rb;
    int koff = (kt & 1) * 64;
#pragma unroll
    for (int it = 0; it < 2; ++it) {
      int r = it * 64 + sr;
      gl_lds16(Asrc + (size_t)(i0 + r) * 128 + koff + sc * 8, sA + (it * 512 + t) * 8);
    }
#pragma unroll
    for (int it = 0; it < 4; ++it) {
      int r = it * 64 + sr;
      gl_lds16(Bsrc + (size_t)r * 128 + koff + sc * 8, sB + (it * 512 + t) * 8);
    }
    __syncthreads();
#pragma unroll
    for (int s = 0; s < 2; ++s) {
      int chunk = ((s * 4 + quad) ^ xorv) * 8;
      bf16x8 av[4], bv[4];
#pragma unroll
      for (int fi = 0; fi < 4; ++fi)
        av[fi] = *(const bf16x8*)(sA + (wm * 64 + fi * 16 + l15) * 64 + chunk);
#pragma unroll
      for (int fj = 0; fj < 4; ++fj)
        bv[fj] = *(const bf16x8*)(sB + (wn * 64 + fj * 16 + l15) * 64 + chunk);
#pragma unroll
      for (int fi = 0; fi < 4; ++fi)
#pragma unroll
        for (int fj = 0; fj < 4; ++fj)
          acc[fi][fj] = __builtin_amdgcn_mfma_f32_16x16x32_bf16(av[fi], bv[fj], acc[fi][fj], 0, 0, 0);
    }
    __syncthreads();
  }

  // two-phase epilogue: 4 waves at a time stage 64x64 bf16 in LDS, store uint2
  for (int ph = 0; ph < 2; ++ph) {
    if (wm == ph) {
      ushort* eb = smem + (w & 3) * 4096;
#pragma unroll
      for (int fj = 0; fj < 4; ++fj) {
        float bias = b1[wn * 64 + fj * 16 + l15];
#pragma unroll
        for (int fi = 0; fi < 4; ++fi)
#pragma unroll
          for (int r = 0; r < 4; ++r) {
            float v = fmaxf(acc[fi][fj][r] + bias, 0.f);
            eb[(fi * 16 + quad * 4 + r) * 64 + fj * 16 + l15] = f2bf(v);
          }
      }
#pragma unroll
      for (int i = 0; i < 16; ++i) {
        int row = i * 4 + (lane >> 4);
        uint2 v = *(const uint2*)(eb + row * 64 + l15 * 4);
        *(uint2*)(h1b + (size_t)(i0 + wm * 64 + row) * 256 + wn * 64 + l15 * 4) = v;
      }
    }
    __syncthreads();
  }
}

// ---------------- MFMA GEMM2 + bias + log_softmax: out[N2,64] fp32 ----------------
__global__ __launch_bounds__(256) void mgemm2_kernel(
    const ushort* __restrict__ aggr2, const ushort* __restrict__ h1b,
    const ushort* __restrict__ W2lb, const ushort* __restrict__ W2rb,
    const float* __restrict__ b2, float* __restrict__ out) {
  __shared__ ushort sA[64 * 64];
  __shared__ ushort sB[64 * 64];
  int t = threadIdx.x;
  int lane = t & 63;
  int w = t >> 6;
  int i0 = blockIdx.x * 64;

  int sr = t >> 3;
  int sc = (t & 7) ^ (sr & 7);
  int quad = lane >> 4;
  int l15 = lane & 15;
  int xorv = lane & 7;

  f32x4 acc[4];
#pragma unroll
  for (int j = 0; j < 4; ++j) acc[j] = (f32x4)(0.f);

  for (int kt = 0; kt < 8; ++kt) {
    const ushort* Asrc = (kt < 4) ? aggr2 : h1b;
    const ushort* Bsrc = (kt < 4) ? W2lb : W2rb;
    int koff = (kt & 3) * 64;
#pragma unroll
    for (int it = 0; it < 2; ++it) {
      int r = it * 32 + sr;
      gl_lds16(Asrc + (size_t)(i0 + r) * 256 + koff + sc * 8, sA + (it * 256 + t) * 8);
    }
#pragma unroll
    for (int it = 0; it < 2; ++it) {
      int r = it * 32 + sr;
      gl_lds16(Bsrc + (size_t)r * 256 + koff + sc * 8, sB + (it * 256 + t) * 8);
    }
    __syncthreads();
#pragma unroll
    for (int s = 0; s < 2; ++s) {
      int chunk = ((s * 4 + quad) ^ xorv) * 8;
      bf16x8 av = *(const bf16x8*)(sA + (w * 16 + l15) * 64 + chunk);
      bf16x8 bv[4];
#pragma unroll
      for (int fj = 0; fj < 4; ++fj)
        bv[fj] = *(const bf16x8*)(sB + (fj * 16 + l15) * 64 + chunk);
#pragma unroll
      for (int fj = 0; fj < 4; ++fj)
        acc[fj] = __builtin_amdgcn_mfma_f32_16x16x32_bf16(av, bv[fj], acc[fj], 0, 0, 0);
    }
    __syncthreads();
  }

  float b2c[4];
#pragma unroll
  for (int fj = 0; fj < 4; ++fj) b2c[fj] = b2[fj * 16 + l15];

#pragma unroll
  for (int r = 0; r < 4; ++r) {
    int row = i0 + w * 16 + quad * 4 + r;
    float v[4];
#pragma unroll
    for (int fj = 0; fj < 4; ++fj) v[fj] = acc[fj][r] + b2c[fj];
    float m = fmaxf(fmaxf(v[0], v[1]), fmaxf(v[2], v[3]));
    m = fmaxf(m, __shfl_xor(m, 1));
    m = fmaxf(m, __shfl_xor(m, 2));
    m = fmaxf(m, __shfl_xor(m, 4));
    m = fmaxf(m, __shfl_xor(m, 8));
    float ssum = __expf(v[0] - m) + __expf(v[1] - m) + __expf(v[2] - m) + __expf(v[3] - m);
    ssum += __shfl_xor(ssum, 1);
    ssum += __shfl_xor(ssum, 2);
    ssum += __shfl_xor(ssum, 4);
    ssum += __shfl_xor(ssum, 8);
    float lg = m + __logf(ssum);
#pragma unroll
    for (int fj = 0; fj < 4; ++fj)
      out[(size_t)row * 64 + fj * 16 + l15] = v[fj] - lg;
  }
}

// ---------------- launch ----------------

extern "C" void kernel_launch(void* const* d_in, const int* in_sizes, int n_in,
                              void* d_out, int out_size, void* d_ws, size_t ws_size,
                              hipStream_t stream) {
  const float* x   = (const float*)d_in[0];
  const int* src1  = (const int*)d_in[1];
  const int* dst1  = (const int*)d_in[2];
  const int* src2  = (const int*)d_in[3];
  const int* dst2  = (const int*)d_in[4];
  const float* W1l = (const float*)d_in[5];
  const float* W1r = (const float*)d_in[6];
  const float* b1  = (const float*)d_in[7];
  const float* W2l = (const float*)d_in[8];
  const float* W2r = (const float*)d_in[9];
  const float* b2  = (const float*)d_in[10];
  float* out = (float*)d_out;

  char* base = (char*)d_ws;
  ushort* xb   = (ushort*)base;                          // N0*128 bf16 = 67.1 MB
  ushort* ag1b = (ushort*)(base + 67108864);             // N1*128 = 16.8 MB
  ushort* ag2b = (ushort*)(base + 83886080);             // N2*256 = 8.4 MB
  uint2* pair1 = (uint2*)(base + 92274688);              // 16.8 MB  (dies at binB)
  uint2* pair2 = (uint2*)(base + 109051904);             // 16.8 MB  (dies at binB)
  ushort* h1b  = (ushort*)(base + 92274688);             // 33.6 MB  (born at mgemm1, aliases pairs)
  int* cnt1  = (int*)(base + 125829120);                 // N1
  int* off1  = cnt1 + N1C;                               // N1
  int* cnt2  = off1 + N1C;                               // N2
  int* off2  = cnt2 + N2C;                               // N2
  int* btail = off2 + N2C;                               // 512
  int* ssrc1 = btail + 512;                              // E1
  int* ssrc2 = ssrc1 + E1C;                              // E2
  ushort* W1lb = (ushort*)(ssrc2 + E2C);                 // 32768
  ushort* W1rb = W1lb + 32768;
  ushort* W2lb = W1rb + 32768;
  ushort* W2rb = W2lb + 16384;

  // weights -> bf16 + btail zero
  cvtw_kernel<<<dim3(32, 5), 256, 0, stream>>>(
      (const float4*)W1l, (const float4*)W1r, (const float4*)W2l, (const float4*)W2r,
      (ushort4*)W1lb, (ushort4*)W1rb, (ushort4*)W2lb, (ushort4*)W2rb, btail);

  // x -> bf16 (67 MB, L3-resident gather source)
  cvtx_kernel<<<4096, 256, 0, stream>>>((const float4*)x, (ushort4*)xb, N0C * 128 / 4);

  // CSR build, both layers, 2 launches
  binA_kernel<<<320, 256, 0, stream>>>(src1, dst1, src2, dst2, btail, pair1, pair2);
  binB_kernel<<<512, 256, 0, stream>>>(pair1, pair2, btail,
                                       off1, cnt1, ssrc1, off2, cnt2, ssrc2);

  // layer 1
  agg1_kernel<<<N1C / 4, 256, 0, stream>>>(xb, ssrc1, off1, cnt1, ag1b);
  mgemm1_kernel<<<N1C / 128, 512, 0, stream>>>(ag1b, xb, W1lb, W1rb, b1, h1b);

  // layer 2
  agg2_kernel<<<N2C / 4, 256, 0, stream>>>(h1b, ssrc2, off2, cnt2, ag2b);
  mgemm2_kernel<<<N2C / 64, 256, 0, stream>>>(ag2b, h1b, W2lb, W2rb, b2, out);
}

// Round 9
// 154.068 us; speedup vs baseline: 19.9586x; 1.0848x over previous
//
#include <hip/hip_runtime.h>
#include <cstdint>
#include <cstddef>

#define N0C 262144
#define N1C 65536
#define N2C 16384
#define E1C 1048576
#define E2C 262144
// IN_C=128, HID_C=256, OUT_C=64
// packed pair: bits 0..17 = src (N0C=2^18), bits 18..25 = dst-local (<=255)

typedef __attribute__((ext_vector_type(8))) short bf16x8;
typedef __attribute__((ext_vector_type(4))) float f32x4;

__device__ __forceinline__ unsigned short f2bf(float f) {
  union { float f; unsigned u; } q; q.f = f;
  unsigned r = q.u + 0x7fffu + ((q.u >> 16) & 1u);
  return (unsigned short)(r >> 16);
}
__device__ __forceinline__ float blo(unsigned u) {
  union { unsigned u; float f; } q; q.u = u << 16; return q.f;
}
__device__ __forceinline__ float bhi(unsigned u) {
  union { unsigned u; float f; } q; q.u = u & 0xffff0000u; return q.f;
}
__device__ __forceinline__ void gl_lds16(const void* g, void* l) {
  __builtin_amdgcn_global_load_lds((const __attribute__((address_space(1))) void*)g,
                                   (__attribute__((address_space(3))) void*)l, 16, 0, 0);
}

// ---------------- fused weight cvt + btail zero ----------------
__global__ __launch_bounds__(256) void cvtw_kernel(
    const float4* __restrict__ W1l, const float4* __restrict__ W1r,
    const float4* __restrict__ W2l, const float4* __restrict__ W2r,
    ushort4* __restrict__ W1lb, ushort4* __restrict__ W1rb,
    ushort4* __restrict__ W2lb, ushort4* __restrict__ W2rb,
    int* __restrict__ btail) {
  int y = blockIdx.y;
  int i = blockIdx.x * 256 + threadIdx.x;
  if (y == 4) {
    if (i < 512) btail[i] = 0;
    return;
  }
  const float4* in; ushort4* outp; int n4;
  if (y == 0)      { in = W1l; outp = W1lb; n4 = 8192; }
  else if (y == 1) { in = W1r; outp = W1rb; n4 = 8192; }
  else if (y == 2) { in = W2l; outp = W2lb; n4 = 4096; }
  else             { in = W2r; outp = W2rb; n4 = 4096; }
  if (i < n4) {
    float4 v = in[i];
    ushort4 o;
    o.x = f2bf(v.x); o.y = f2bf(v.y); o.z = f2bf(v.z); o.w = f2bf(v.w);
    outp[i] = o;
  }
}

// ---------------- mega: binA (blocks 0..319, packed pairs) + cvtx (blocks 320..2367) ----
__global__ __launch_bounds__(256) void mega_kernel(
    const int* __restrict__ src1, const int* __restrict__ dst1,
    const int* __restrict__ src2, const int* __restrict__ dst2,
    int* __restrict__ btail, unsigned* __restrict__ pair1, unsigned* __restrict__ pair2,
    const float4* __restrict__ x, ushort4* __restrict__ xb) {
  __shared__ int hist[256];
  __shared__ int lofs[256];
  __shared__ int gbase[256];
  __shared__ unsigned stg[4096];
  __shared__ unsigned char bstg[4096];
  int b = blockIdx.x;
  int t = threadIdx.x;
  if (b >= 320) {
    // cvtx role: x -> bf16, grid-stride over 2048 blocks
    int i = (b - 320) * 256 + t;
    const int stride = 2048 * 256;
    const int n4 = N0C * 128 / 4;
    for (; i < n4; i += stride) {
      float4 v = x[i];
      ushort4 o;
      o.x = f2bf(v.x); o.y = f2bf(v.y); o.z = f2bf(v.z); o.w = f2bf(v.w);
      xb[i] = o;
    }
    return;
  }
  // binA role
  const int* src; const int* dst; int shift; int dmask; int* bt; unsigned* pb; int e0;
  if (b < 256) { src = src1; dst = dst1; shift = 8; dmask = 255; bt = btail;       pb = pair1; e0 = b * 4096; }
  else         { src = src2; dst = dst2; shift = 6; dmask = 63;  bt = btail + 256; pb = pair2; e0 = (b - 256) * 4096; }
  hist[t] = 0;
  __syncthreads();
  unsigned pk[16]; int bk[16], rk[16];
#pragma unroll
  for (int k = 0; k < 16; ++k) {
    int e = e0 + k * 256 + t;
    int s = src[e];
    int d = dst[e];
    bk[k] = d >> shift;
    pk[k] = ((unsigned)(d & dmask) << 18) | (unsigned)s;
    rk[k] = atomicAdd(&hist[bk[k]], 1);
  }
  __syncthreads();
  int v = hist[t];
  lofs[t] = v;
  __syncthreads();
  for (int ofs = 1; ofs < 256; ofs <<= 1) {
    int add = (t >= ofs) ? lofs[t - ofs] : 0;
    __syncthreads();
    lofs[t] += add;
    __syncthreads();
  }
  gbase[t] = atomicAdd(&bt[t], v);
  int excl = lofs[t] - v;
  lofs[t] = excl;
  __syncthreads();
#pragma unroll
  for (int k = 0; k < 16; ++k) {
    int p = lofs[bk[k]] + rk[k];
    stg[p] = pk[k];
    bstg[p] = (unsigned char)bk[k];
  }
  __syncthreads();
  for (int i = t; i < 4096; i += 256) {
    int bki = bstg[i];
    int idx = gbase[bki] + (i - lofs[bki]);
    if (idx < 8192)
      pb[(size_t)bki * 8192 + idx] = stg[i];
  }
}

// binB: one block per BUCKET (layer1: 0..255, layer2: 256..511), packed uint pairs.
__global__ __launch_bounds__(256) void binB_kernel(
    const unsigned* __restrict__ pair1, const unsigned* __restrict__ pair2,
    const int* __restrict__ btail,
    int* __restrict__ off1, int* __restrict__ cnt1, int* __restrict__ ssrc1,
    int* __restrict__ off2, int* __restrict__ cnt2, int* __restrict__ ssrc2) {
  __shared__ int lcnt[256];
  __shared__ int loff[256];
  __shared__ int lcnt2[256];
  __shared__ unsigned stage[8192];
  int b = blockIdx.x;
  int t = threadIdx.x;
  const unsigned* pb; const int* bt; int dpb; int* off; int* cnt; int* ssrc; int bl;
  if (b < 256) { bl = b;       pb = pair1 + (size_t)bl * 8192; bt = btail;       dpb = 256; off = off1; cnt = cnt1; ssrc = ssrc1; }
  else         { bl = b - 256; pb = pair2 + (size_t)bl * 8192; bt = btail + 256; dpb = 64;  off = off2; cnt = cnt2; ssrc = ssrc2; }
  // base = sum(bt[0..bl)) via LDS reduce
  lcnt[t] = (t < bl) ? bt[t] : 0;
  __syncthreads();
  for (int ofs = 128; ofs > 0; ofs >>= 1) {
    if (t < ofs) lcnt[t] += lcnt[t + ofs];
    __syncthreads();
  }
  int base = lcnt[0];
  __syncthreads();
  lcnt[t] = 0;
  lcnt2[t] = 0;
  __syncthreads();
  int n = bt[bl];
  if (n > 8192) n = 8192;
  for (int i = t; i < n; i += 256) {
    unsigned p = pb[i];
    atomicAdd(&lcnt[p >> 18], 1);
  }
  __syncthreads();
  int v = lcnt[t];
  loff[t] = v;
  __syncthreads();
  for (int ofs = 1; ofs < 256; ofs <<= 1) {
    int add = (t >= ofs) ? loff[t - ofs] : 0;
    __syncthreads();
    loff[t] += add;
    __syncthreads();
  }
  int excl = loff[t] - v;
  loff[t] = excl;
  if (t < dpb) {
    cnt[bl * dpb + t] = v;
    off[bl * dpb + t] = base + excl;
  }
  __syncthreads();
  for (int i = t; i < n; i += 256) {
    unsigned p = pb[i];
    int dl = p >> 18;
    int r = atomicAdd(&lcnt2[dl], 1);
    stage[loff[dl] + r] = p & 0x3FFFFu;
  }
  __syncthreads();
  for (int i = t; i < n; i += 256) ssrc[base + i] = (int)stage[i];
}

// ---------------- layer-1 aggregation: bf16 gather, 8 edges in flight ----------------
__global__ __launch_bounds__(256) void agg1_kernel(const ushort* __restrict__ xb,
                                                   const int* __restrict__ ssrc,
                                                   const int* __restrict__ off,
                                                   const int* __restrict__ cnt,
                                                   ushort* __restrict__ aggr) {
  int wid = (blockIdx.x * 256 + threadIdx.x) >> 6;
  int lane = threadIdx.x & 63;
  int grp = lane >> 4;
  int cl = lane & 15;
  int start = __builtin_amdgcn_readfirstlane(off[wid]);
  int n = __builtin_amdgcn_readfirstlane(cnt[wid]);
  float a0 = 0.f, a1 = 0.f, a2 = 0.f, a3 = 0.f, a4 = 0.f, a5 = 0.f, a6 = 0.f, a7 = 0.f;
  int j = 0;
  for (; j + 8 <= n; j += 8) {
    int sa = ssrc[start + j + grp];
    int sb = ssrc[start + j + 4 + grp];
    uint4 va = *(const uint4*)(xb + (size_t)sa * 128 + cl * 8);
    uint4 vb = *(const uint4*)(xb + (size_t)sb * 128 + cl * 8);
    a0 += blo(va.x) + blo(vb.x); a1 += bhi(va.x) + bhi(vb.x);
    a2 += blo(va.y) + blo(vb.y); a3 += bhi(va.y) + bhi(vb.y);
    a4 += blo(va.z) + blo(vb.z); a5 += bhi(va.z) + bhi(vb.z);
    a6 += blo(va.w) + blo(vb.w); a7 += bhi(va.w) + bhi(vb.w);
  }
  if (j + 4 <= n) {
    int s = ssrc[start + j + grp];
    uint4 v = *(const uint4*)(xb + (size_t)s * 128 + cl * 8);
    a0 += blo(v.x); a1 += bhi(v.x); a2 += blo(v.y); a3 += bhi(v.y);
    a4 += blo(v.z); a5 += bhi(v.z); a6 += blo(v.w); a7 += bhi(v.w);
    j += 4;
  }
  if (grp < n - j) {
    int s = ssrc[start + j + grp];
    uint4 v = *(const uint4*)(xb + (size_t)s * 128 + cl * 8);
    a0 += blo(v.x); a1 += bhi(v.x); a2 += blo(v.y); a3 += bhi(v.y);
    a4 += blo(v.z); a5 += bhi(v.z); a6 += blo(v.w); a7 += bhi(v.w);
  }
#define RED1(v) v += __shfl_xor(v, 16); v += __shfl_xor(v, 32);
  RED1(a0) RED1(a1) RED1(a2) RED1(a3) RED1(a4) RED1(a5) RED1(a6) RED1(a7)
#undef RED1
  if (lane < 16) {
    float inv = (n > 0) ? 1.0f / (float)n : 0.f;
    uint4 o;
    o.x = (unsigned)f2bf(a0 * inv) | ((unsigned)f2bf(a1 * inv) << 16);
    o.y = (unsigned)f2bf(a2 * inv) | ((unsigned)f2bf(a3 * inv) << 16);
    o.z = (unsigned)f2bf(a4 * inv) | ((unsigned)f2bf(a5 * inv) << 16);
    o.w = (unsigned)f2bf(a6 * inv) | ((unsigned)f2bf(a7 * inv) << 16);
    *(uint4*)(aggr + (size_t)wid * 128 + cl * 8) = o;
  }
}

// ---------------- layer-2 aggregation: bf16 gather from h1b, 8 edges in flight -------
__global__ __launch_bounds__(256) void agg2_kernel(const ushort* __restrict__ h1b,
                                                   const int* __restrict__ ssrc,
                                                   const int* __restrict__ off,
                                                   const int* __restrict__ cnt,
                                                   ushort* __restrict__ aggr) {
  int wid = (blockIdx.x * 256 + threadIdx.x) >> 6;
  int lane = threadIdx.x & 63;
  int grp = lane >> 5;
  int cl = lane & 31;
  int start = __builtin_amdgcn_readfirstlane(off[wid]);
  int n = __builtin_amdgcn_readfirstlane(cnt[wid]);
  float a0 = 0.f, a1 = 0.f, a2 = 0.f, a3 = 0.f, a4 = 0.f, a5 = 0.f, a6 = 0.f, a7 = 0.f;
  int j = 0;
  for (; j + 8 <= n; j += 8) {
    int s0 = ssrc[start + j + grp];
    int s1 = ssrc[start + j + 2 + grp];
    int s2 = ssrc[start + j + 4 + grp];
    int s3 = ssrc[start + j + 6 + grp];
    uint4 v0 = *(const uint4*)(h1b + (size_t)s0 * 256 + cl * 8);
    uint4 v1 = *(const uint4*)(h1b + (size_t)s1 * 256 + cl * 8);
    uint4 v2 = *(const uint4*)(h1b + (size_t)s2 * 256 + cl * 8);
    uint4 v3 = *(const uint4*)(h1b + (size_t)s3 * 256 + cl * 8);
    a0 += blo(v0.x) + blo(v1.x) + blo(v2.x) + blo(v3.x);
    a1 += bhi(v0.x) + bhi(v1.x) + bhi(v2.x) + bhi(v3.x);
    a2 += blo(v0.y) + blo(v1.y) + blo(v2.y) + blo(v3.y);
    a3 += bhi(v0.y) + bhi(v1.y) + bhi(v2.y) + bhi(v3.y);
    a4 += blo(v0.z) + blo(v1.z) + blo(v2.z) + blo(v3.z);
    a5 += bhi(v0.z) + bhi(v1.z) + bhi(v2.z) + bhi(v3.z);
    a6 += blo(v0.w) + blo(v1.w) + blo(v2.w) + blo(v3.w);
    a7 += bhi(v0.w) + bhi(v1.w) + bhi(v2.w) + bhi(v3.w);
  }
  for (; j + 2 <= n; j += 2) {
    int s = ssrc[start + j + grp];
    uint4 v = *(const uint4*)(h1b + (size_t)s * 256 + cl * 8);
    a0 += blo(v.x); a1 += bhi(v.x); a2 += blo(v.y); a3 += bhi(v.y);
    a4 += blo(v.z); a5 += bhi(v.z); a6 += blo(v.w); a7 += bhi(v.w);
  }
  if (grp < n - j) {
    int s = ssrc[start + j + grp];
    uint4 v = *(const uint4*)(h1b + (size_t)s * 256 + cl * 8);
    a0 += blo(v.x); a1 += bhi(v.x); a2 += blo(v.y); a3 += bhi(v.y);
    a4 += blo(v.z); a5 += bhi(v.z); a6 += blo(v.w); a7 += bhi(v.w);
  }
#define RED2(v) v += __shfl_xor(v, 32);
  RED2(a0) RED2(a1) RED2(a2) RED2(a3) RED2(a4) RED2(a5) RED2(a6) RED2(a7)
#undef RED2
  if (lane < 32) {
    float inv = (n > 0) ? 1.0f / (float)n : 0.f;
    uint4 o;
    o.x = (unsigned)f2bf(a0 * inv) | ((unsigned)f2bf(a1 * inv) << 16);
    o.y = (unsigned)f2bf(a2 * inv) | ((unsigned)f2bf(a3 * inv) << 16);
    o.z = (unsigned)f2bf(a4 * inv) | ((unsigned)f2bf(a5 * inv) << 16);
    o.w = (unsigned)f2bf(a6 * inv) | ((unsigned)f2bf(a7 * inv) << 16);
    *(uint4*)(aggr + (size_t)wid * 256 + cl * 8) = o;
  }
}

// ---------------- MFMA GEMM1: [N1,256] = relu([aggr1|xb] @ [W1l|W1r]^T + b1), bf16 out
__global__ __launch_bounds__(512) void mgemm1_kernel(
    const ushort* __restrict__ aggr1, const ushort* __restrict__ xb,
    const ushort* __restrict__ W1lb, const ushort* __restrict__ W1rb,
    const float* __restrict__ b1, ushort* __restrict__ h1b) {
  __shared__ ushort smem[24576];   // sA 8192 + sB 16384 ushorts = 48KB
  ushort* sA = smem;
  ushort* sB = smem + 8192;
  int t = threadIdx.x;
  int lane = t & 63;
  int w = t >> 6;
  int wm = w >> 2, wn = w & 3;
  int i0 = blockIdx.x * 128;

  int sr = t >> 3;
  int sc = (t & 7) ^ (sr & 7);
  int quad = lane >> 4;
  int l15 = lane & 15;
  int xorv = lane & 7;

  f32x4 acc[4][4];
#pragma unroll
  for (int i = 0; i < 4; ++i)
#pragma unroll
    for (int j = 0; j < 4; ++j) acc[i][j] = (f32x4)(0.f);

  for (int kt = 0; kt < 4; ++kt) {
    const ushort* Asrc = (kt < 2) ? aggr1 : xb;
    const ushort* Bsrc = (kt < 2) ? W1lb : W1rb;
    int koff = (kt & 1) * 64;
#pragma unroll
    for (int it = 0; it < 2; ++it) {
      int r = it * 64 + sr;
      gl_lds16(Asrc + (size_t)(i0 + r) * 128 + koff + sc * 8, sA + (it * 512 + t) * 8);
    }
#pragma unroll
    for (int it = 0; it < 4; ++it) {
      int r = it * 64 + sr;
      gl_lds16(Bsrc + (size_t)r * 128 + koff + sc * 8, sB + (it * 512 + t) * 8);
    }
    __syncthreads();
#pragma unroll
    for (int s = 0; s < 2; ++s) {
      int chunk = ((s * 4 + quad) ^ xorv) * 8;
      bf16x8 av[4], bv[4];
#pragma unroll
      for (int fi = 0; fi < 4; ++fi)
        av[fi] = *(const bf16x8*)(sA + (wm * 64 + fi * 16 + l15) * 64 + chunk);
#pragma unroll
      for (int fj = 0; fj < 4; ++fj)
        bv[fj] = *(const bf16x8*)(sB + (wn * 64 + fj * 16 + l15) * 64 + chunk);
#pragma unroll
      for (int fi = 0; fi < 4; ++fi)
#pragma unroll
        for (int fj = 0; fj < 4; ++fj)
          acc[fi][fj] = __builtin_amdgcn_mfma_f32_16x16x32_bf16(av[fi], bv[fj], acc[fi][fj], 0, 0, 0);
    }
    __syncthreads();
  }

  // two-phase epilogue: 4 waves at a time stage 64x64 bf16 in LDS, store uint2
  for (int ph = 0; ph < 2; ++ph) {
    if (wm == ph) {
      ushort* eb = smem + (w & 3) * 4096;
#pragma unroll
      for (int fj = 0; fj < 4; ++fj) {
        float bias = b1[wn * 64 + fj * 16 + l15];
#pragma unroll
        for (int fi = 0; fi < 4; ++fi)
#pragma unroll
          for (int r = 0; r < 4; ++r) {
            float v = fmaxf(acc[fi][fj][r] + bias, 0.f);
            eb[(fi * 16 + quad * 4 + r) * 64 + fj * 16 + l15] = f2bf(v);
          }
      }
#pragma unroll
      for (int i = 0; i < 16; ++i) {
        int row = i * 4 + (lane >> 4);
        uint2 v = *(const uint2*)(eb + row * 64 + l15 * 4);
        *(uint2*)(h1b + (size_t)(i0 + wm * 64 + row) * 256 + wn * 64 + l15 * 4) = v;
      }
    }
    __syncthreads();
  }
}

// ---------------- MFMA GEMM2 + bias + log_softmax: out[N2,64] fp32 ----------------
__global__ __launch_bounds__(256) void mgemm2_kernel(
    const ushort* __restrict__ aggr2, const ushort* __restrict__ h1b,
    const ushort* __restrict__ W2lb, const ushort* __restrict__ W2rb,
    const float* __restrict__ b2, float* __restrict__ out) {
  __shared__ ushort sA[64 * 64];
  __shared__ ushort sB[64 * 64];
  int t = threadIdx.x;
  int lane = t & 63;
  int w = t >> 6;
  int i0 = blockIdx.x * 64;

  int sr = t >> 3;
  int sc = (t & 7) ^ (sr & 7);
  int quad = lane >> 4;
  int l15 = lane & 15;
  int xorv = lane & 7;

  f32x4 acc[4];
#pragma unroll
  for (int j = 0; j < 4; ++j) acc[j] = (f32x4)(0.f);

  for (int kt = 0; kt < 8; ++kt) {
    const ushort* Asrc = (kt < 4) ? aggr2 : h1b;
    const ushort* Bsrc = (kt < 4) ? W2lb : W2rb;
    int koff = (kt & 3) * 64;
#pragma unroll
    for (int it = 0; it < 2; ++it) {
      int r = it * 32 + sr;
      gl_lds16(Asrc + (size_t)(i0 + r) * 256 + koff + sc * 8, sA + (it * 256 + t) * 8);
    }
#pragma unroll
    for (int it = 0; it < 2; ++it) {
      int r = it * 32 + sr;
      gl_lds16(Bsrc + (size_t)r * 256 + koff + sc * 8, sB + (it * 256 + t) * 8);
    }
    __syncthreads();
#pragma unroll
    for (int s = 0; s < 2; ++s) {
      int chunk = ((s * 4 + quad) ^ xorv) * 8;
      bf16x8 av = *(const bf16x8*)(sA + (w * 16 + l15) * 64 + chunk);
      bf16x8 bv[4];
#pragma unroll
      for (int fj = 0; fj < 4; ++fj)
        bv[fj] = *(const bf16x8*)(sB + (fj * 16 + l15) * 64 + chunk);
#pragma unroll
      for (int fj = 0; fj < 4; ++fj)
        acc[fj] = __builtin_amdgcn_mfma_f32_16x16x32_bf16(av, bv[fj], acc[fj], 0, 0, 0);
    }
    __syncthreads();
  }

  float b2c[4];
#pragma unroll
  for (int fj = 0; fj < 4; ++fj) b2c[fj] = b2[fj * 16 + l15];

#pragma unroll
  for (int r = 0; r < 4; ++r) {
    int row = i0 + w * 16 + quad * 4 + r;
    float v[4];
#pragma unroll
    for (int fj = 0; fj < 4; ++fj) v[fj] = acc[fj][r] + b2c[fj];
    float m = fmaxf(fmaxf(v[0], v[1]), fmaxf(v[2], v[3]));
    m = fmaxf(m, __shfl_xor(m, 1));
    m = fmaxf(m, __shfl_xor(m, 2));
    m = fmaxf(m, __shfl_xor(m, 4));
    m = fmaxf(m, __shfl_xor(m, 8));
    float ssum = __expf(v[0] - m) + __expf(v[1] - m) + __expf(v[2] - m) + __expf(v[3] - m);
    ssum += __shfl_xor(ssum, 1);
    ssum += __shfl_xor(ssum, 2);
    ssum += __shfl_xor(ssum, 4);
    ssum += __shfl_xor(ssum, 8);
    float lg = m + __logf(ssum);
#pragma unroll
    for (int fj = 0; fj < 4; ++fj)
      out[(size_t)row * 64 + fj * 16 + l15] = v[fj] - lg;
  }
}

// ---------------- launch ----------------

extern "C" void kernel_launch(void* const* d_in, const int* in_sizes, int n_in,
                              void* d_out, int out_size, void* d_ws, size_t ws_size,
                              hipStream_t stream) {
  const float* x   = (const float*)d_in[0];
  const int* src1  = (const int*)d_in[1];
  const int* dst1  = (const int*)d_in[2];
  const int* src2  = (const int*)d_in[3];
  const int* dst2  = (const int*)d_in[4];
  const float* W1l = (const float*)d_in[5];
  const float* W1r = (const float*)d_in[6];
  const float* b1  = (const float*)d_in[7];
  const float* W2l = (const float*)d_in[8];
  const float* W2r = (const float*)d_in[9];
  const float* b2  = (const float*)d_in[10];
  float* out = (float*)d_out;

  char* base = (char*)d_ws;
  ushort* xb   = (ushort*)base;                          // 67.1 MB
  ushort* ag1b = (ushort*)(base + 67108864);             // 16.8 MB
  ushort* ag2b = (ushort*)(base + 83886080);             // 8.4 MB
  unsigned* pair1 = (unsigned*)(base + 92274688);        // 8.4 MB
  unsigned* pair2 = (unsigned*)(base + 100663296);       // 8.4 MB
  ushort* h1b  = (ushort*)(base + 109051904);            // 33.6 MB
  int* cnt1  = (int*)(base + 142606336);                 // N1
  int* off1  = cnt1 + N1C;                               // N1
  int* cnt2  = off1 + N1C;                               // N2
  int* off2  = cnt2 + N2C;                               // N2
  int* btail = off2 + N2C;                               // 512
  int* ssrc1 = btail + 512;                              // E1
  int* ssrc2 = ssrc1 + E1C;                              // E2
  ushort* W1lb = (ushort*)(ssrc2 + E2C);                 // 32768
  ushort* W1rb = W1lb + 32768;
  ushort* W2lb = W1rb + 32768;
  ushort* W2rb = W2lb + 16384;

  // weights -> bf16 + btail zero (must precede mega's binA atomics)
  cvtw_kernel<<<dim3(32, 5), 256, 0, stream>>>(
      (const float4*)W1l, (const float4*)W1r, (const float4*)W2l, (const float4*)W2r,
      (ushort4*)W1lb, (ushort4*)W1rb, (ushort4*)W2lb, (ushort4*)W2rb, btail);

  // binA (320 blocks) + cvtx (2048 blocks) fused, overlapping
  mega_kernel<<<2368, 256, 0, stream>>>(src1, dst1, src2, dst2, btail, pair1, pair2,
                                        (const float4*)x, (ushort4*)xb);

  // fine sort per bucket
  binB_kernel<<<512, 256, 0, stream>>>(pair1, pair2, btail,
                                       off1, cnt1, ssrc1, off2, cnt2, ssrc2);

  // layer 1
  agg1_kernel<<<N1C / 4, 256, 0, stream>>>(xb, ssrc1, off1, cnt1, ag1b);
  mgemm1_kernel<<<N1C / 128, 512, 0, stream>>>(ag1b, xb, W1lb, W1rb, b1, h1b);

  // layer 2
  agg2_kernel<<<N2C / 4, 256, 0, stream>>>(h1b, ssrc2, off2, cnt2, ag2b);
  mgemm2_kernel<<<N2C / 64, 256, 0, stream>>>(ag2b, h1b, W2lb, W2rb, b2, out);
}